// Round 1
// baseline (2014.806 us; speedup 1.0000x reference)
//
#include <hip/hip_runtime.h>

#define TT 512
#define NB 64
#define HH 128
#define G4 512
#define HDIM 256

typedef __bf16 bf16x8 __attribute__((ext_vector_type(8)));
typedef float f32x4 __attribute__((ext_vector_type(4)));
typedef unsigned int u32x4 __attribute__((ext_vector_type(4)));

union FragU { u32x4 u4; bf16x8 bf; unsigned short us[8]; };

__device__ __forceinline__ unsigned short f2bf(float f){
  unsigned u = __builtin_bit_cast(unsigned, f);
  return (unsigned short)((u + 0x7FFFu + ((u>>16)&1u)) >> 16);
}
__device__ __forceinline__ float bf2f(unsigned short h){
  unsigned u = ((unsigned)h) << 16;
  return __builtin_bit_cast(float, u);
}
__device__ __forceinline__ float sigf(float x){ return 1.0f/(1.0f + __expf(-x)); }
__device__ __forceinline__ float tanhf_fast(float x){
  float e = __expf(-2.0f*fabsf(x));
  float t = (1.0f - e)/(1.0f + e);
  return (x >= 0.f) ? t : -t;
}

// ---------------- prep kernels ----------------

__global__ __launch_bounds__(256) void k_prep_bias(
    const float* __restrict__ bi0, const float* __restrict__ bh0,
    const float* __restrict__ bi1, const float* __restrict__ bh1,
    float* __restrict__ bias0, float* __restrict__ bias1)
{
  int id = blockIdx.x*256 + threadIdx.x;   // < 2048
  if (id < 1024) bias0[id] = bi0[id] + bh0[id];
  else { int k = id - 1024; bias1[k] = bi1[k] + bh1[k]; }
}

// Bp[kb][c][j] = w_ih[dir][n][kb*8+j]  (c = dir*512+n), zero-padded in k
__global__ __launch_bounds__(256) void k_prep_b(
    const float* __restrict__ w_ih, unsigned short* __restrict__ Bp,
    const int Ksrc, const int Kpad)
{
  int id = blockIdx.x*256 + threadIdx.x;   // < Kpad*1024
  int k = id >> 10, c = id & 1023;
  if (k >= Kpad) return;
  int dir = c >> 9, n = c & 511;
  float v = (k < Ksrc) ? w_ih[((size_t)(dir*512 + n))*Ksrc + k] : 0.f;
  Bp[(((size_t)(k>>3))*1024 + c)*8 + (k&7)] = f2bf(v);
}

// x_emb[row][c] bf16, row = t*64+b, padded to 320 cols
__global__ __launch_bounds__(320) void k_embed(
    const int* __restrict__ word, const float* __restrict__ emb,
    unsigned short* __restrict__ xe)
{
  int row = blockIdx.x;       // 0..32767
  int c = threadIdx.x;        // 0..319
  int t = row >> 6, b = row & 63;
  int wd = word[b*TT + t];
  float v = (c < 300) ? emb[(size_t)wd*300 + c] : 0.f;
  xe[(size_t)row*320 + c] = f2bf(v);
}

// ---------------- input GEMM: xp = A(32768 x K) * Bp(K x 1024) + bias ----------------
// output scattered to xp[dir][bg][t][gate 512][b 16] bf16

__global__ __launch_bounds__(256) void k_gemm(
    const unsigned short* __restrict__ A,   // [32768][lda] bf16
    const unsigned short* __restrict__ Bp,  // [K/8][1024][8] bf16
    const float* __restrict__ bias,         // [1024]
    unsigned short* __restrict__ xp,
    const int lda, const int KB)
{
  const int tid = threadIdx.x;
  const int l = tid & 63, w = tid >> 6;
  const int quad = l >> 4, lo = l & 15;
  const int wm = w >> 1, wn = w & 1;
  const int M0 = blockIdx.x * 128;
  const int N0 = blockIdx.y * 128;

  __shared__ __align__(16) unsigned short Asl[4*128*8];  // [q][m][8]
  __shared__ __align__(16) unsigned short Bsl[4*128*8];  // [q][n][8]

  f32x4 acc[4][4] = {};

  for (int kb=0; kb<KB; ++kb){
    const int k0 = kb*32;
    u32x4 va[2], vb[2];
    #pragma unroll
    for (int hh=0; hh<2; ++hh){
      const int cch = tid + hh*256;
      const int q = cch >> 7, mm = cch & 127;
      va[hh] = *(const u32x4*)(A + (size_t)(M0+mm)*lda + k0 + q*8);
      vb[hh] = *(const u32x4*)(Bp + (((size_t)((k0>>3)+q))*1024 + N0 + mm)*8);
    }
    __syncthreads();   // WAR vs previous iteration's frag reads
    #pragma unroll
    for (int hh=0; hh<2; ++hh){
      const int cch = tid + hh*256;
      *(u32x4*)&Asl[cch*8] = va[hh];
      *(u32x4*)&Bsl[cch*8] = vb[hh];
    }
    __syncthreads();

    FragU af[4], bfg[4];
    #pragma unroll
    for (int mt=0; mt<4; ++mt)
      af[mt].u4 = *(const u32x4*)&Asl[((quad<<7) + wm*64 + mt*16 + lo)*8];
    #pragma unroll
    for (int nt=0; nt<4; ++nt)
      bfg[nt].u4 = *(const u32x4*)&Bsl[((quad<<7) + wn*64 + nt*16 + lo)*8];
    #pragma unroll
    for (int mt=0; mt<4; ++mt)
      #pragma unroll
      for (int nt=0; nt<4; ++nt)
        acc[mt][nt] = __builtin_amdgcn_mfma_f32_16x16x32_bf16(af[mt].bf, bfg[nt].bf, acc[mt][nt], 0, 0, 0);
  }

  #pragma unroll
  for (int mt=0; mt<4; ++mt){
    #pragma unroll
    for (int nt=0; nt<4; ++nt){
      const int col = N0 + wn*64 + nt*16 + lo;
      const int dir = col >> 9, n = col & 511;
      const float bv = bias[col];
      #pragma unroll
      for (int r=0; r<4; ++r){
        const int row = M0 + wm*64 + mt*16 + quad*4 + r;
        const int t = row >> 6, b = row & 63;
        const size_t o = ((((size_t)(dir*4 + (b>>4)))*TT + t)*G4 + n)*16 + (b & 15);
        xp[o] = f2bf(acc[mt][nt][r] + bv);
      }
    }
  }
}

// ---------------- BiLSTM scan ----------------
// 8 WGs: bid = dir*4 + bg; each WG: 16 sequences, 512 steps.
// GEMM per step: D[gate 512][batch 16] = W(512x128) * h(128x16), MFMA 16x16x32 bf16.
// Wave w owns gate-tiles {w, 8+w, 16+w, 24+w} -> i/f/g/o of a unit are in the same lane/reg.

__global__ __launch_bounds__(512) void k_scan(
    const float* __restrict__ w_hh,          // [2][512][128]
    const unsigned short* __restrict__ xp,   // [dir][bg][t][512][16] bf16
    unsigned short* __restrict__ xout)       // [t][64][256] bf16
{
  const int bid = blockIdx.x;           // 0..7
  const int dir = bid >> 2, bg = bid & 3;
  const int tid = threadIdx.x;
  const int l = tid & 63, w = tid >> 6;
  const int quad = l >> 4, lo = l & 15;

  // static weight A-frags: A[m=lo within tile][k=quad*8+j]
  FragU afr[4][4];
  {
    const float* wb = w_hh + (size_t)dir*G4*HH;
    #pragma unroll
    for (int g=0; g<4; ++g){
      const int m = g*HH + w*16 + lo;
      #pragma unroll
      for (int kq=0; kq<4; ++kq){
        const float* p = wb + (size_t)m*HH + kq*32 + quad*8;
        #pragma unroll
        for (int j=0; j<8; ++j) afr[g][kq].us[j] = f2bf(p[j]);
      }
    }
  }

  __shared__ __align__(16) unsigned short hbuf[2][16][136];  // [buf][batch][k] bf16, +8 pad
  for (int i = tid; i < 2*16*136; i += 512) ((unsigned short*)hbuf)[i] = 0;
  __syncthreads();

  float c[4] = {0.f,0.f,0.f,0.f};
  const unsigned short* xpb = xp + ((size_t)bid)*TT*G4*16;
  const int t0 = dir ? (TT-1) : 0;
  const int dt = dir ? -1 : 1;
  const int dirOff = dir * HH;
  const int jbase = w*16 + quad*4;

  unsigned short xs[16];
  {
    const unsigned short* p = xpb + (size_t)t0*G4*16;
    #pragma unroll
    for (int g=0; g<4; ++g)
      #pragma unroll
      for (int r=0; r<4; ++r)
        xs[g*4+r] = p[(g*HH + jbase + r)*16 + lo];
  }

  int cur = 0;
  for (int it=0; it<TT; ++it){
    const int t = t0 + dt*it;
    const int tn = (it+1 < TT) ? (t + dt) : t;

    // acc init = xp (bias already folded in)
    f32x4 acc[4];
    #pragma unroll
    for (int g=0; g<4; ++g){
      #pragma unroll
      for (int r=0; r<4; ++r) acc[g][r] = bf2f(xs[g*4+r]);
    }

    // prefetch next step's xp into registers (hide HBM/L3 latency behind MFMA+epilogue)
    unsigned short xn[16];
    {
      const unsigned short* p = xpb + (size_t)tn*G4*16;
      #pragma unroll
      for (int g=0; g<4; ++g)
        #pragma unroll
        for (int r=0; r<4; ++r)
          xn[g*4+r] = p[(g*HH + jbase + r)*16 + lo];
    }

    // B-frags: B[k][n=batch] = h[batch][k]
    FragU bfr[4];
    #pragma unroll
    for (int kq=0; kq<4; ++kq)
      bfr[kq].u4 = *(const u32x4*)&hbuf[cur][lo][kq*32 + quad*8];

    #pragma unroll
    for (int kq=0; kq<4; ++kq)
      #pragma unroll
      for (int g=0; g<4; ++g)
        acc[g] = __builtin_amdgcn_mfma_f32_16x16x32_bf16(afr[g][kq].bf, bfr[kq].bf, acc[g], 0, 0, 0);

    // epilogue: lane has unit (j = jbase+r, batch = lo); gates i/f/g/o = acc[0..3][r]
    const int nxt = cur ^ 1;
    const size_t rowb = (((size_t)t*NB) + bg*16 + lo)*HDIM + dirOff + jbase;
    #pragma unroll
    for (int r=0; r<4; ++r){
      float gi = acc[0][r], gf = acc[1][r], gg = acc[2][r], go = acc[3][r];
      float ct = sigf(gf)*c[r] + sigf(gi)*tanhf_fast(gg);
      c[r] = ct;
      float h = sigf(go)*tanhf_fast(ct);
      unsigned short hb = f2bf(h);
      hbuf[nxt][lo][jbase + r] = hb;
      xout[rowb + r] = hb;
    }
    __syncthreads();   // single barrier: h double-buffered
    #pragma unroll
    for (int i=0;i<16;++i) xs[i] = xn[i];
    cur = nxt;
  }
}

// ---------------- emission GEMM: em[b][t][l] = x2 row . w_out[l] + b_out[l] ----------------

__global__ __launch_bounds__(256) void k_em(
    const unsigned short* __restrict__ x2,  // [32768][256] bf16
    const float* __restrict__ w_out,        // [9][256]
    const float* __restrict__ b_out,        // [9]
    float* __restrict__ em)                 // [64][512][9]
{
  const int tid = threadIdx.x;
  const int l = tid & 63, w = tid >> 6;
  const int quad = l >> 4, lo = l & 15;
  const int M0 = blockIdx.x*128 + w*32;

  FragU bf[8];
  #pragma unroll
  for (int kq=0; kq<8; ++kq){
    #pragma unroll
    for (int j=0; j<8; ++j){
      float v = (lo < 9) ? w_out[lo*HDIM + kq*32 + quad*8 + j] : 0.f;
      bf[kq].us[j] = f2bf(v);
    }
  }

  f32x4 acc[2] = {};
  #pragma unroll
  for (int kq=0; kq<8; ++kq){
    FragU a0, a1;
    a0.u4 = *(const u32x4*)(x2 + ((size_t)(M0 + lo))*HDIM + kq*32 + quad*8);
    a1.u4 = *(const u32x4*)(x2 + ((size_t)(M0 + 16 + lo))*HDIM + kq*32 + quad*8);
    acc[0] = __builtin_amdgcn_mfma_f32_16x16x32_bf16(a0.bf, bf[kq].bf, acc[0], 0, 0, 0);
    acc[1] = __builtin_amdgcn_mfma_f32_16x16x32_bf16(a1.bf, bf[kq].bf, acc[1], 0, 0, 0);
  }

  if (lo < 9){
    const float bo = b_out[lo];
    #pragma unroll
    for (int mt=0; mt<2; ++mt){
      #pragma unroll
      for (int r=0; r<4; ++r){
        const int row = M0 + mt*16 + quad*4 + r;
        const int t = row >> 6, b = row & 63;
        em[((size_t)b*TT + t)*9 + lo] = acc[mt][r] + bo;
      }
    }
  }
}

// ---------------- CRF: log-semiring matrix tree reduction ----------------

__global__ __launch_bounds__(256) void k_crf_build(
    const int* __restrict__ word, const float* __restrict__ em,
    const float* __restrict__ start_t, const float* __restrict__ trans,
    float* __restrict__ G0)                 // [64][512][81]
{
  int id = blockIdx.x*256 + threadIdx.x;    // < 64*512*81
  int b = id / (TT*81);
  int rem = id - b*(TT*81);
  int t = rem / 81;
  int ij = rem - t*81;
  int i = ij / 9, j = ij - i*9;
  float e = em[((size_t)b*TT + t)*9 + j];
  float v;
  if (t == 0) v = start_t[j] + e;                       // row-independent
  else if (word[b*TT + t] > 0) v = trans[i*9 + j] + e;
  else v = (i == j) ? 0.f : -1e30f;                     // LSE-identity
  G0[(size_t)id] = v;
}

// dst = radix-8 LSE-matmul reduction of src groups (order-preserving)
__global__ __launch_bounds__(128) void k_crf_reduce(
    const float* __restrict__ src, float* __restrict__ dst, const int nm)
{
  const int bid = blockIdx.x;
  const int ng = nm >> 3;
  const int b = bid / ng, g = bid - b*ng;
  const int tid = threadIdx.x;
  __shared__ float R[2][81];
  const float* base = src + ((size_t)b*nm + g*8)*81;
  if (tid < 81) R[0][tid] = base[tid];
  int cur = 0;
  for (int s=1; s<8; ++s){
    __syncthreads();
    if (tid < 81){
      int i = tid/9, j = tid - (tid/9)*9;
      const float* M = base + (size_t)s*81;
      float a[9], mx = -3.0e38f;
      #pragma unroll
      for (int k=0;k<9;++k){ a[k] = R[cur][i*9+k] + M[k*9+j]; mx = fmaxf(mx, a[k]); }
      float sm = 0.f;
      #pragma unroll
      for (int k=0;k<9;++k) sm += __expf(a[k]-mx);
      R[cur^1][tid] = mx + __logf(sm);
    }
    cur ^= 1;
  }
  __syncthreads();
  if (tid < 81) dst[((size_t)b*ng + g)*81 + tid] = R[cur][tid];
}

__global__ __launch_bounds__(256) void k_crf_num(
    const int* __restrict__ word, const int* __restrict__ label,
    const float* __restrict__ em, const float* __restrict__ start_t,
    const float* __restrict__ end_t, const float* __restrict__ trans,
    float* __restrict__ numv)
{
  const int b = blockIdx.x, tid = threadIdx.x;
  __shared__ float sred[256];
  __shared__ int ssend;
  int ms = 0;
  for (int t=tid; t<TT; t+=256) ms += (word[b*TT+t] > 0) ? 1 : 0;
  sred[tid] = (float)ms;
  __syncthreads();
  for (int st=128; st>0; st>>=1){ if (tid<st) sred[tid] += sred[tid+st]; __syncthreads(); }
  if (tid==0) ssend = (int)sred[0] - 1;
  __syncthreads();
  const int send = ssend;
  float part = 0.f;
  for (int t=tid; t<TT; t+=256){
    int tag = label[b*TT+t];
    float es = em[((size_t)b*TT+t)*9 + tag];
    if (t == 0) part += start_t[tag] + es;
    else if (word[b*TT+t] > 0) part += trans[label[b*TT+t-1]*9 + tag] + es;
    if (t == send) part += end_t[tag];
  }
  __syncthreads();
  sred[tid] = part;
  __syncthreads();
  for (int st=128; st>0; st>>=1){ if (tid<st) sred[tid] += sred[tid+st]; __syncthreads(); }
  if (tid==0) numv[b] = sred[0];
}

__global__ __launch_bounds__(64) void k_final(
    const float* __restrict__ numv, const float* __restrict__ G3,
    const float* __restrict__ end_t, float* __restrict__ out)
{
  const int b = threadIdx.x;  // 0..63
  float a[9], mx = -3.0e38f;
  #pragma unroll
  for (int j=0;j<9;++j){ a[j] = G3[b*81 + j] + end_t[j]; mx = fmaxf(mx, a[j]); }
  float sm = 0.f;
  #pragma unroll
  for (int j=0;j<9;++j) sm += __expf(a[j]-mx);
  float denom = mx + __logf(sm);
  float v = numv[b] - denom;
  #pragma unroll
  for (int off=32; off>0; off>>=1) v += __shfl_down(v, off, 64);
  if (b == 0) out[0] = -v;
}

// ---------------- launch ----------------

extern "C" void kernel_launch(void* const* d_in, const int* in_sizes, int n_in,
                              void* d_out, int out_size, void* d_ws, size_t ws_size,
                              hipStream_t stream)
{
  (void)in_sizes; (void)n_in; (void)out_size; (void)ws_size;
  const int*   word  = (const int*)d_in[0];
  const int*   label = (const int*)d_in[1];
  const float* emb   = (const float*)d_in[2];
  const float* w_ih0 = (const float*)d_in[3];
  const float* w_hh0 = (const float*)d_in[4];
  const float* b_ih0 = (const float*)d_in[5];
  const float* b_hh0 = (const float*)d_in[6];
  const float* w_ih1 = (const float*)d_in[7];
  const float* w_hh1 = (const float*)d_in[8];
  const float* b_ih1 = (const float*)d_in[9];
  const float* b_hh1 = (const float*)d_in[10];
  const float* w_out = (const float*)d_in[11];
  const float* b_out = (const float*)d_in[12];
  const float* start_t = (const float*)d_in[13];
  const float* end_t   = (const float*)d_in[14];
  const float* trans   = (const float*)d_in[15];

  char* ws = (char*)d_ws;
  unsigned short* xp    = (unsigned short*)(ws + 0);            // 67108864 B
  unsigned short* xe    = (unsigned short*)(ws + 67108864);     // 20971520 B (dead after gemm0)
  float*          G0    = (float*)(ws + 67108864);              // overlay on xe (10616832 B)
  unsigned short* x1    = (unsigned short*)(ws + 88080384);     // 16777216 B
  unsigned short* x2    = (unsigned short*)(ws + 104857600);    // 16777216 B
  unsigned short* Bp0   = (unsigned short*)(ws + 121634816);    // 655360 B
  unsigned short* Bp1   = (unsigned short*)(ws + 122290176);    // 524288 B
  float*          bias0 = (float*)(ws + 122814464);             // 4096 B
  float*          bias1 = (float*)(ws + 122818560);             // 4096 B
  float*          em    = (float*)(ws + 122822656);             // 1179648 B
  float*          G1    = (float*)(ws + 124002304);             // 1327104 B
  float*          G2    = (float*)(ws + 125329408);             // 165888 B
  float*          G3    = (float*)(ws + 125495296);             // 20736 B
  float*          numv  = (float*)(ws + 125516032);             // 256 B

  hipLaunchKernelGGL(k_prep_bias, dim3(8), dim3(256), 0, stream, b_ih0, b_hh0, b_ih1, b_hh1, bias0, bias1);
  hipLaunchKernelGGL(k_prep_b, dim3(1280), dim3(256), 0, stream, w_ih0, Bp0, 300, 320);
  hipLaunchKernelGGL(k_prep_b, dim3(1024), dim3(256), 0, stream, w_ih1, Bp1, 256, 256);
  hipLaunchKernelGGL(k_embed, dim3(32768), dim3(320), 0, stream, word, emb, xe);
  hipLaunchKernelGGL(k_gemm, dim3(256, 8), dim3(256), 0, stream, xe, Bp0, bias0, xp, 320, 10);
  hipLaunchKernelGGL(k_scan, dim3(8), dim3(512), 0, stream, w_hh0, xp, x1);
  hipLaunchKernelGGL(k_gemm, dim3(256, 8), dim3(256), 0, stream, x1, Bp1, bias1, xp, 256, 8);
  hipLaunchKernelGGL(k_scan, dim3(8), dim3(512), 0, stream, w_hh1, xp, x2);
  hipLaunchKernelGGL(k_em, dim3(256), dim3(256), 0, stream, x2, w_out, b_out, em);
  hipLaunchKernelGGL(k_crf_build, dim3(10368), dim3(256), 0, stream, word, em, start_t, trans, G0);
  hipLaunchKernelGGL(k_crf_reduce, dim3(4096), dim3(128), 0, stream, G0, G1, 512);
  hipLaunchKernelGGL(k_crf_reduce, dim3(512), dim3(128), 0, stream, G1, G2, 64);
  hipLaunchKernelGGL(k_crf_reduce, dim3(64), dim3(128), 0, stream, G2, G3, 8);
  hipLaunchKernelGGL(k_crf_num, dim3(64), dim3(256), 0, stream, word, label, em, start_t, end_t, trans, numv);
  hipLaunchKernelGGL(k_final, dim3(1), dim3(64), 0, stream, numv, G3, end_t, (float*)d_out);
}

// Round 2
// 1840.889 us; speedup vs baseline: 1.0945x; 1.0945x over previous
//
#include <hip/hip_runtime.h>

#define TT 512
#define NB 64
#define HH 128
#define G4 512
#define HDIM 256

typedef __bf16 bf16x8 __attribute__((ext_vector_type(8)));
typedef float f32x4 __attribute__((ext_vector_type(4)));
typedef unsigned int u32x4 __attribute__((ext_vector_type(4)));
typedef unsigned int u32x2 __attribute__((ext_vector_type(2)));

union FragU { u32x4 u4; bf16x8 bf; unsigned short us[8]; };
union PF2 { u32x4 v[2]; unsigned short us[16]; };

__device__ __forceinline__ unsigned short f2bf(float f){
  unsigned u = __builtin_bit_cast(unsigned, f);
  return (unsigned short)((u + 0x7FFFu + ((u>>16)&1u)) >> 16);
}
__device__ __forceinline__ float bf2f(unsigned short h){
  unsigned u = ((unsigned)h) << 16;
  return __builtin_bit_cast(float, u);
}
__device__ __forceinline__ float sigf(float x){
  return __builtin_amdgcn_rcpf(1.0f + __builtin_amdgcn_exp2f(-1.442695041f*x));
}
__device__ __forceinline__ float tanh_s(float x){
  // tanh(x) = 2*sigmoid(2x) - 1  (sign-correct, no select)
  return __builtin_fmaf(2.0f, __builtin_amdgcn_rcpf(1.0f + __builtin_amdgcn_exp2f(-2.885390082f*x)), -1.0f);
}

// ---------------- prep kernels ----------------

__global__ __launch_bounds__(256) void k_prep_bias(
    const float* __restrict__ bi0, const float* __restrict__ bh0,
    const float* __restrict__ bi1, const float* __restrict__ bh1,
    float* __restrict__ bias0, float* __restrict__ bias1)
{
  int id = blockIdx.x*256 + threadIdx.x;   // < 2048
  if (id < 1024) bias0[id] = bi0[id] + bh0[id];
  else { int k = id - 1024; bias1[k] = bi1[k] + bh1[k]; }
}

// Bp[kb][c][j] = w_ih[dir][n][kb*8+j]  (c = dir*512+n), zero-padded in k
__global__ __launch_bounds__(256) void k_prep_b(
    const float* __restrict__ w_ih, unsigned short* __restrict__ Bp,
    const int Ksrc, const int Kpad)
{
  int id = blockIdx.x*256 + threadIdx.x;   // < Kpad*1024
  int k = id >> 10, c = id & 1023;
  if (k >= Kpad) return;
  int dir = c >> 9, n = c & 511;
  float v = (k < Ksrc) ? w_ih[((size_t)(dir*512 + n))*Ksrc + k] : 0.f;
  Bp[(((size_t)(k>>3))*1024 + c)*8 + (k&7)] = f2bf(v);
}

// x_emb[row][c] bf16, row = t*64+b, padded to 320 cols
__global__ __launch_bounds__(320) void k_embed(
    const int* __restrict__ word, const float* __restrict__ emb,
    unsigned short* __restrict__ xe)
{
  int row = blockIdx.x;       // 0..32767
  int c = threadIdx.x;        // 0..319
  int t = row >> 6, b = row & 63;
  int wd = word[b*TT + t];
  float v = (c < 300) ? emb[(size_t)wd*300 + c] : 0.f;
  xe[(size_t)row*320 + c] = f2bf(v);
}

// ---------------- input GEMM: xp = A(32768 x K) * Bp(K x 1024) + bias ----------------
// output scattered to xp[bid][t][w][lane][slot16] bf16  (scan frag-order layout)

__global__ __launch_bounds__(256) void k_gemm(
    const unsigned short* __restrict__ A,   // [32768][lda] bf16
    const unsigned short* __restrict__ Bp,  // [K/8][1024][8] bf16
    const float* __restrict__ bias,         // [1024]
    unsigned short* __restrict__ xp,
    const int lda, const int KB)
{
  const int tid = threadIdx.x;
  const int l = tid & 63, w = tid >> 6;
  const int quad = l >> 4, lo = l & 15;
  const int wm = w >> 1, wn = w & 1;
  const int M0 = blockIdx.x * 128;
  const int N0 = blockIdx.y * 128;

  __shared__ __align__(16) unsigned short Asl[4*128*8];  // [q][m][8]
  __shared__ __align__(16) unsigned short Bsl[4*128*8];  // [q][n][8]

  f32x4 acc[4][4] = {};

  for (int kb=0; kb<KB; ++kb){
    const int k0 = kb*32;
    u32x4 va[2], vb[2];
    #pragma unroll
    for (int hh=0; hh<2; ++hh){
      const int cch = tid + hh*256;
      const int q = cch >> 7, mm = cch & 127;
      va[hh] = *(const u32x4*)(A + (size_t)(M0+mm)*lda + k0 + q*8);
      vb[hh] = *(const u32x4*)(Bp + (((size_t)((k0>>3)+q))*1024 + N0 + mm)*8);
    }
    __syncthreads();   // WAR vs previous iteration's frag reads
    #pragma unroll
    for (int hh=0; hh<2; ++hh){
      const int cch = tid + hh*256;
      *(u32x4*)&Asl[cch*8] = va[hh];
      *(u32x4*)&Bsl[cch*8] = vb[hh];
    }
    __syncthreads();

    FragU af[4], bfg[4];
    #pragma unroll
    for (int mt=0; mt<4; ++mt)
      af[mt].u4 = *(const u32x4*)&Asl[((quad<<7) + wm*64 + mt*16 + lo)*8];
    #pragma unroll
    for (int nt=0; nt<4; ++nt)
      bfg[nt].u4 = *(const u32x4*)&Bsl[((quad<<7) + wn*64 + nt*16 + lo)*8];
    #pragma unroll
    for (int mt=0; mt<4; ++mt)
      #pragma unroll
      for (int nt=0; nt<4; ++nt)
        acc[mt][nt] = __builtin_amdgcn_mfma_f32_16x16x32_bf16(af[mt].bf, bfg[nt].bf, acc[mt][nt], 0, 0, 0);
  }

  #pragma unroll
  for (int mt=0; mt<4; ++mt){
    #pragma unroll
    for (int nt=0; nt<4; ++nt){
      const int col = N0 + wn*64 + nt*16 + lo;
      const int dir = col >> 9, n = col & 511;
      const float bv = bias[col];
      const int wS = (n >> 4) & 7;               // scan wave
      const int qS = (n >> 2) & 3;               // scan quad
      const int sS = ((n >> 7) << 2) + (n & 3);  // scan slot
      #pragma unroll
      for (int r=0; r<4; ++r){
        const int row = M0 + wm*64 + mt*16 + quad*4 + r;
        const int t = row >> 6, b = row & 63;
        const int bid = dir*4 + (b >> 4);
        const int lS = qS*16 + (b & 15);
        const size_t o = ((((size_t)bid*TT + t)*8 + wS)*64 + lS)*16 + sS;
        xp[o] = f2bf(acc[mt][nt][r] + bv);
      }
    }
  }
}

// ---------------- BiLSTM scan ----------------
// 8 WGs: bid = dir*4 + bg; each WG: 16 sequences, 512 steps.
// GEMM per step: D[gate 512][batch 16] = W(512x128) * h(128x16), MFMA 16x16x32 bf16.
// Wave w owns gate-tiles {w, 8+w, 16+w, 24+w} -> i/f/g/o of a unit in same lane/reg.
// Raw barrier (lgkmcnt-only) keeps VMEM (xp prefetch, xout stores) off the
// per-step critical path; xp is pre-scattered so each lane loads 32 B contiguous.

__global__ __launch_bounds__(512) void k_scan(
    const float* __restrict__ w_hh,          // [2][512][128]
    const unsigned short* __restrict__ xp,   // [bid][t][w][lane][16] bf16
    unsigned short* __restrict__ xout)       // [t][64][256] bf16
{
  const int bid = blockIdx.x;           // 0..7
  const int dir = bid >> 2, bg = bid & 3;
  const int tid = threadIdx.x;
  const int l = tid & 63, w = tid >> 6;
  const int quad = l >> 4, lo = l & 15;

  // static weight A-frags: A[m=lo within tile][k=quad*8+j]
  FragU afr[4][4];
  {
    const float* wb = w_hh + (size_t)dir*G4*HH;
    #pragma unroll
    for (int g=0; g<4; ++g){
      const int m = g*HH + w*16 + lo;
      #pragma unroll
      for (int kq=0; kq<4; ++kq){
        const float* p = wb + (size_t)m*HH + kq*32 + quad*8;
        #pragma unroll
        for (int j=0; j<8; ++j) afr[g][kq].us[j] = f2bf(p[j]);
      }
    }
  }

  __shared__ __align__(16) unsigned short hbuf[2][16][136];  // [buf][batch][k], +8 pad
  for (int i = tid; i < 2*16*136; i += 512) ((unsigned short*)hbuf)[i] = 0;
  __syncthreads();

  float c[4] = {0.f,0.f,0.f,0.f};
  const int t0 = dir ? (TT-1) : 0;
  const int dt = dir ? -1 : 1;
  const int dirOff = dir * HH;
  const int jbase = w*16 + quad*4;
  const unsigned short* xpb = xp + ((size_t)bid*TT*8 + w)*1024 + l*16;

  // depth-2 register prefetch of xp (32 B/lane, 2x dwordx4)
  PF2 pf[2];
  pf[0].v[0] = *(const u32x4*)(xpb + (size_t)t0*8192);
  pf[0].v[1] = *(const u32x4*)(xpb + (size_t)t0*8192 + 8);
  {
    const int t1 = t0 + dt;
    pf[1].v[0] = *(const u32x4*)(xpb + (size_t)t1*8192);
    pf[1].v[1] = *(const u32x4*)(xpb + (size_t)t1*8192 + 8);
  }

  int cur = 0;
  for (int it=0; it<TT; ++it){
    const int t = t0 + dt*it;
    const int pb = it & 1;

    // acc init = xp (bias already folded in)
    f32x4 acc[4];
    #pragma unroll
    for (int g=0; g<4; ++g)
      #pragma unroll
      for (int r=0; r<4; ++r) acc[g][r] = bf2f(pf[pb].us[g*4+r]);

    // issue prefetch for step it+2 into the buffer just consumed
    {
      const int it2 = (it+2 < TT) ? (it+2) : (TT-1);
      const int t2 = t0 + dt*it2;
      pf[pb].v[0] = *(const u32x4*)(xpb + (size_t)t2*8192);
      pf[pb].v[1] = *(const u32x4*)(xpb + (size_t)t2*8192 + 8);
    }

    // B-frags: B[k][n=batch] = h[batch][k]
    FragU bfr[4];
    #pragma unroll
    for (int kq=0; kq<4; ++kq)
      bfr[kq].u4 = *(const u32x4*)&hbuf[cur][lo][kq*32 + quad*8];

    #pragma unroll
    for (int kq=0; kq<4; ++kq)
      #pragma unroll
      for (int g=0; g<4; ++g)
        acc[g] = __builtin_amdgcn_mfma_f32_16x16x32_bf16(afr[g][kq].bf, bfr[kq].bf, acc[g], 0, 0, 0);

    // epilogue: lane has unit (j = jbase+r, batch = lo); gates i/f/g/o = acc[0..3][r]
    const int nxt = cur ^ 1;
    unsigned short hb[4];
    #pragma unroll
    for (int r=0; r<4; ++r){
      float gi = acc[0][r], gf = acc[1][r], gg = acc[2][r], go = acc[3][r];
      float ct = __builtin_fmaf(sigf(gf), c[r], sigf(gi)*tanh_s(gg));
      c[r] = ct;
      hb[r] = f2bf(sigf(go)*tanh_s(ct));
    }
    u32x2 hv;
    hv.x = (unsigned)hb[0] | ((unsigned)hb[1] << 16);
    hv.y = (unsigned)hb[2] | ((unsigned)hb[3] << 16);
    *(u32x2*)&hbuf[nxt][lo][jbase] = hv;
    *(u32x2*)(xout + (((size_t)t*NB) + bg*16 + lo)*HDIM + dirOff + jbase) = hv;

    // raw barrier: wait LDS only — no vmcnt drain of prefetch loads / xout stores
    asm volatile("s_waitcnt lgkmcnt(0)\n\ts_barrier" ::: "memory");
    cur = nxt;
  }
}

// ---------------- emission GEMM: em[b][t][l] = x2 row . w_out[l] + b_out[l] ----------------

__global__ __launch_bounds__(256) void k_em(
    const unsigned short* __restrict__ x2,  // [32768][256] bf16
    const float* __restrict__ w_out,        // [9][256]
    const float* __restrict__ b_out,        // [9]
    float* __restrict__ em)                 // [64][512][9]
{
  const int tid = threadIdx.x;
  const int l = tid & 63, w = tid >> 6;
  const int quad = l >> 4, lo = l & 15;
  const int M0 = blockIdx.x*128 + w*32;

  FragU bf[8];
  #pragma unroll
  for (int kq=0; kq<8; ++kq){
    #pragma unroll
    for (int j=0; j<8; ++j){
      float v = (lo < 9) ? w_out[lo*HDIM + kq*32 + quad*8 + j] : 0.f;
      bf[kq].us[j] = f2bf(v);
    }
  }

  f32x4 acc[2] = {};
  #pragma unroll
  for (int kq=0; kq<8; ++kq){
    FragU a0, a1;
    a0.u4 = *(const u32x4*)(x2 + ((size_t)(M0 + lo))*HDIM + kq*32 + quad*8);
    a1.u4 = *(const u32x4*)(x2 + ((size_t)(M0 + 16 + lo))*HDIM + kq*32 + quad*8);
    acc[0] = __builtin_amdgcn_mfma_f32_16x16x32_bf16(a0.bf, bf[kq].bf, acc[0], 0, 0, 0);
    acc[1] = __builtin_amdgcn_mfma_f32_16x16x32_bf16(a1.bf, bf[kq].bf, acc[1], 0, 0, 0);
  }

  if (lo < 9){
    const float bo = b_out[lo];
    #pragma unroll
    for (int mt=0; mt<2; ++mt){
      #pragma unroll
      for (int r=0; r<4; ++r){
        const int row = M0 + mt*16 + quad*4 + r;
        const int t = row >> 6, b = row & 63;
        em[((size_t)b*TT + t)*9 + lo] = acc[mt][r] + bo;
      }
    }
  }
}

// ---------------- CRF: log-semiring matrix tree reduction ----------------

__global__ __launch_bounds__(256) void k_crf_build(
    const int* __restrict__ word, const float* __restrict__ em,
    const float* __restrict__ start_t, const float* __restrict__ trans,
    float* __restrict__ G0)                 // [64][512][81]
{
  int id = blockIdx.x*256 + threadIdx.x;    // < 64*512*81
  int b = id / (TT*81);
  int rem = id - b*(TT*81);
  int t = rem / 81;
  int ij = rem - t*81;
  int i = ij / 9, j = ij - i*9;
  float e = em[((size_t)b*TT + t)*9 + j];
  float v;
  if (t == 0) v = start_t[j] + e;                       // row-independent
  else if (word[b*TT + t] > 0) v = trans[i*9 + j] + e;
  else v = (i == j) ? 0.f : -1e30f;                     // LSE-identity
  G0[(size_t)id] = v;
}

// dst = radix-8 LSE-matmul reduction of src groups (order-preserving)
__global__ __launch_bounds__(128) void k_crf_reduce(
    const float* __restrict__ src, float* __restrict__ dst, const int nm)
{
  const int bid = blockIdx.x;
  const int ng = nm >> 3;
  const int b = bid / ng, g = bid - b*ng;
  const int tid = threadIdx.x;
  __shared__ float R[2][81];
  const float* base = src + ((size_t)b*nm + g*8)*81;
  if (tid < 81) R[0][tid] = base[tid];
  int cur = 0;
  for (int s=1; s<8; ++s){
    __syncthreads();
    if (tid < 81){
      int i = tid/9, j = tid - (tid/9)*9;
      const float* M = base + (size_t)s*81;
      float a[9], mx = -3.0e38f;
      #pragma unroll
      for (int k=0;k<9;++k){ a[k] = R[cur][i*9+k] + M[k*9+j]; mx = fmaxf(mx, a[k]); }
      float sm = 0.f;
      #pragma unroll
      for (int k=0;k<9;++k) sm += __expf(a[k]-mx);
      R[cur^1][tid] = mx + __logf(sm);
    }
    cur ^= 1;
  }
  __syncthreads();
  if (tid < 81) dst[((size_t)b*ng + g)*81 + tid] = R[cur][tid];
}

__global__ __launch_bounds__(256) void k_crf_num(
    const int* __restrict__ word, const int* __restrict__ label,
    const float* __restrict__ em, const float* __restrict__ start_t,
    const float* __restrict__ end_t, const float* __restrict__ trans,
    float* __restrict__ numv)
{
  const int b = blockIdx.x, tid = threadIdx.x;
  __shared__ float sred[256];
  __shared__ int ssend;
  int ms = 0;
  for (int t=tid; t<TT; t+=256) ms += (word[b*TT+t] > 0) ? 1 : 0;
  sred[tid] = (float)ms;
  __syncthreads();
  for (int st=128; st>0; st>>=1){ if (tid<st) sred[tid] += sred[tid+st]; __syncthreads(); }
  if (tid==0) ssend = (int)sred[0] - 1;
  __syncthreads();
  const int send = ssend;
  float part = 0.f;
  for (int t=tid; t<TT; t+=256){
    int tag = label[b*TT+t];
    float es = em[((size_t)b*TT+t)*9 + tag];
    if (t == 0) part += start_t[tag] + es;
    else if (word[b*TT+t] > 0) part += trans[label[b*TT+t-1]*9 + tag] + es;
    if (t == send) part += end_t[tag];
  }
  __syncthreads();
  sred[tid] = part;
  __syncthreads();
  for (int st=128; st>0; st>>=1){ if (tid<st) sred[tid] += sred[tid+st]; __syncthreads(); }
  if (tid==0) numv[b] = sred[0];
}

__global__ __launch_bounds__(64) void k_final(
    const float* __restrict__ numv, const float* __restrict__ G3,
    const float* __restrict__ end_t, float* __restrict__ out)
{
  const int b = threadIdx.x;  // 0..63
  float a[9], mx = -3.0e38f;
  #pragma unroll
  for (int j=0;j<9;++j){ a[j] = G3[b*81 + j] + end_t[j]; mx = fmaxf(mx, a[j]); }
  float sm = 0.f;
  #pragma unroll
  for (int j=0;j<9;++j) sm += __expf(a[j]-mx);
  float denom = mx + __logf(sm);
  float v = numv[b] - denom;
  #pragma unroll
  for (int off=32; off>0; off>>=1) v += __shfl_down(v, off, 64);
  if (b == 0) out[0] = -v;
}

// ---------------- launch ----------------

extern "C" void kernel_launch(void* const* d_in, const int* in_sizes, int n_in,
                              void* d_out, int out_size, void* d_ws, size_t ws_size,
                              hipStream_t stream)
{
  (void)in_sizes; (void)n_in; (void)out_size; (void)ws_size;
  const int*   word  = (const int*)d_in[0];
  const int*   label = (const int*)d_in[1];
  const float* emb   = (const float*)d_in[2];
  const float* w_ih0 = (const float*)d_in[3];
  const float* w_hh0 = (const float*)d_in[4];
  const float* b_ih0 = (const float*)d_in[5];
  const float* b_hh0 = (const float*)d_in[6];
  const float* w_ih1 = (const float*)d_in[7];
  const float* w_hh1 = (const float*)d_in[8];
  const float* b_ih1 = (const float*)d_in[9];
  const float* b_hh1 = (const float*)d_in[10];
  const float* w_out = (const float*)d_in[11];
  const float* b_out = (const float*)d_in[12];
  const float* start_t = (const float*)d_in[13];
  const float* end_t   = (const float*)d_in[14];
  const float* trans   = (const float*)d_in[15];

  char* ws = (char*)d_ws;
  unsigned short* xp    = (unsigned short*)(ws + 0);            // 67108864 B
  unsigned short* xe    = (unsigned short*)(ws + 67108864);     // 20971520 B (dead after gemm0)
  float*          G0    = (float*)(ws + 67108864);              // overlay on xe (10616832 B)
  unsigned short* x1    = (unsigned short*)(ws + 88080384);     // 16777216 B
  unsigned short* x2    = (unsigned short*)(ws + 104857600);    // 16777216 B
  unsigned short* Bp0   = (unsigned short*)(ws + 121634816);    // 655360 B
  unsigned short* Bp1   = (unsigned short*)(ws + 122290176);    // 524288 B
  float*          bias0 = (float*)(ws + 122814464);             // 4096 B
  float*          bias1 = (float*)(ws + 122818560);             // 4096 B
  float*          em    = (float*)(ws + 122822656);             // 1179648 B
  float*          G1    = (float*)(ws + 124002304);             // 1327104 B
  float*          G2    = (float*)(ws + 125329408);             // 165888 B
  float*          G3    = (float*)(ws + 125495296);             // 20736 B
  float*          numv  = (float*)(ws + 125516032);             // 256 B

  hipLaunchKernelGGL(k_prep_bias, dim3(8), dim3(256), 0, stream, b_ih0, b_hh0, b_ih1, b_hh1, bias0, bias1);
  hipLaunchKernelGGL(k_prep_b, dim3(1280), dim3(256), 0, stream, w_ih0, Bp0, 300, 320);
  hipLaunchKernelGGL(k_prep_b, dim3(1024), dim3(256), 0, stream, w_ih1, Bp1, 256, 256);
  hipLaunchKernelGGL(k_embed, dim3(32768), dim3(320), 0, stream, word, emb, xe);
  hipLaunchKernelGGL(k_gemm, dim3(256, 8), dim3(256), 0, stream, xe, Bp0, bias0, xp, 320, 10);
  hipLaunchKernelGGL(k_scan, dim3(8), dim3(512), 0, stream, w_hh0, xp, x1);
  hipLaunchKernelGGL(k_gemm, dim3(256, 8), dim3(256), 0, stream, x1, Bp1, bias1, xp, 256, 8);
  hipLaunchKernelGGL(k_scan, dim3(8), dim3(512), 0, stream, w_hh1, xp, x2);
  hipLaunchKernelGGL(k_em, dim3(256), dim3(256), 0, stream, x2, w_out, b_out, em);
  hipLaunchKernelGGL(k_crf_build, dim3(10368), dim3(256), 0, stream, word, em, start_t, trans, G0);
  hipLaunchKernelGGL(k_crf_reduce, dim3(4096), dim3(128), 0, stream, G0, G1, 512);
  hipLaunchKernelGGL(k_crf_reduce, dim3(512), dim3(128), 0, stream, G1, G2, 64);
  hipLaunchKernelGGL(k_crf_reduce, dim3(64), dim3(128), 0, stream, G2, G3, 8);
  hipLaunchKernelGGL(k_crf_num, dim3(64), dim3(256), 0, stream, word, label, em, start_t, end_t, trans, numv);
  hipLaunchKernelGGL(k_final, dim3(1), dim3(64), 0, stream, numv, G3, end_t, (float*)d_out);
}

// Round 3
// 1180.706 us; speedup vs baseline: 1.7064x; 1.5591x over previous
//
#include <hip/hip_runtime.h>

#define TT 512
#define NB 64
#define HH 128
#define G4 512
#define HDIM 256

typedef __bf16 bf16x8 __attribute__((ext_vector_type(8)));
typedef float f32x4 __attribute__((ext_vector_type(4)));
typedef unsigned int u32x4 __attribute__((ext_vector_type(4)));
typedef unsigned int u32x2 __attribute__((ext_vector_type(2)));

union FragU { u32x4 u4; bf16x8 bf; unsigned short us[8]; };
union PF2 { u32x4 v[2]; unsigned short us[16]; };

#define SC_SIG  -1.442695041f   // fold: sigma(x) = rcp(1 + exp2(-log2e * x))
#define SC_TANH -2.885390082f   // fold: tanh(x)  = 2*rcp(1 + exp2(-2log2e * x)) - 1

__device__ __forceinline__ unsigned short f2bf(float f){
  unsigned u = __builtin_bit_cast(unsigned, f);
  return (unsigned short)((u + 0x7FFFu + ((u>>16)&1u)) >> 16);
}
__device__ __forceinline__ float bf2f(unsigned short h){
  unsigned u = ((unsigned)h) << 16;
  return __builtin_bit_cast(float, u);
}
// y is pre-scaled by SC_SIG (or SC_TANH): returns sigma
__device__ __forceinline__ float rsig(float y){
  return __builtin_amdgcn_rcpf(1.0f + __builtin_amdgcn_exp2f(y));
}

// ---------------- prep kernels ----------------

__global__ __launch_bounds__(256) void k_prep_bias(
    const float* __restrict__ bi0, const float* __restrict__ bh0,
    const float* __restrict__ bi1, const float* __restrict__ bh1,
    float* __restrict__ bias0, float* __restrict__ bias1)
{
  int id = blockIdx.x*256 + threadIdx.x;   // < 2048
  int n = id & 511;
  float s = ((n >> 7) == 2) ? SC_TANH : SC_SIG;
  if (id < 1024) bias0[id] = (bi0[id] + bh0[id]) * s;
  else { int k = id - 1024; bias1[k] = (bi1[k] + bh1[k]) * s; }
}

// Bp[kb][c][j] = w_ih[dir][n][kb*8+j] * gate_scale  (c = dir*512+n), zero-padded in k
__global__ __launch_bounds__(256) void k_prep_b(
    const float* __restrict__ w_ih, unsigned short* __restrict__ Bp,
    const int Ksrc, const int Kpad)
{
  int id = blockIdx.x*256 + threadIdx.x;   // < Kpad*1024
  int k = id >> 10, c = id & 1023;
  if (k >= Kpad) return;
  int dir = c >> 9, n = c & 511;
  float s = ((n >> 7) == 2) ? SC_TANH : SC_SIG;
  float v = (k < Ksrc) ? w_ih[((size_t)(dir*512 + n))*Ksrc + k] * s : 0.f;
  Bp[(((size_t)(k>>3))*1024 + c)*8 + (k&7)] = f2bf(v);
}

// x_emb[row][c] bf16, row = t*64+b, padded to 320 cols
__global__ __launch_bounds__(320) void k_embed(
    const int* __restrict__ word, const float* __restrict__ emb,
    unsigned short* __restrict__ xe)
{
  int row = blockIdx.x;       // 0..32767
  int c = threadIdx.x;        // 0..319
  int t = row >> 6, b = row & 63;
  int wd = word[b*TT + t];
  float v = (c < 300) ? emb[(size_t)wd*300 + c] : 0.f;
  xe[(size_t)row*320 + c] = f2bf(v);
}

// ---------------- input GEMM: xp = A(32768 x K) * Bp(K x 1024) + bias ----------------
// output scattered to xp[bid][t][w][lane][slot16] bf16  (scan frag-order layout)

__global__ __launch_bounds__(256) void k_gemm(
    const unsigned short* __restrict__ A,   // [32768][lda] bf16
    const unsigned short* __restrict__ Bp,  // [K/8][1024][8] bf16
    const float* __restrict__ bias,         // [1024]
    unsigned short* __restrict__ xp,
    const int lda, const int KB)
{
  const int tid = threadIdx.x;
  const int l = tid & 63, w = tid >> 6;
  const int quad = l >> 4, lo = l & 15;
  const int wm = w >> 1, wn = w & 1;
  const int M0 = blockIdx.x * 128;
  const int N0 = blockIdx.y * 128;

  __shared__ __align__(16) unsigned short Asl[4*128*8];  // [q][m][8]
  __shared__ __align__(16) unsigned short Bsl[4*128*8];  // [q][n][8]

  f32x4 acc[4][4] = {};

  for (int kb=0; kb<KB; ++kb){
    const int k0 = kb*32;
    u32x4 va[2], vb[2];
    #pragma unroll
    for (int hh=0; hh<2; ++hh){
      const int cch = tid + hh*256;
      const int q = cch >> 7, mm = cch & 127;
      va[hh] = *(const u32x4*)(A + (size_t)(M0+mm)*lda + k0 + q*8);
      vb[hh] = *(const u32x4*)(Bp + (((size_t)((k0>>3)+q))*1024 + N0 + mm)*8);
    }
    __syncthreads();   // WAR vs previous iteration's frag reads
    #pragma unroll
    for (int hh=0; hh<2; ++hh){
      const int cch = tid + hh*256;
      *(u32x4*)&Asl[cch*8] = va[hh];
      *(u32x4*)&Bsl[cch*8] = vb[hh];
    }
    __syncthreads();

    FragU af[4], bfg[4];
    #pragma unroll
    for (int mt=0; mt<4; ++mt)
      af[mt].u4 = *(const u32x4*)&Asl[((quad<<7) + wm*64 + mt*16 + lo)*8];
    #pragma unroll
    for (int nt=0; nt<4; ++nt)
      bfg[nt].u4 = *(const u32x4*)&Bsl[((quad<<7) + wn*64 + nt*16 + lo)*8];
    #pragma unroll
    for (int mt=0; mt<4; ++mt)
      #pragma unroll
      for (int nt=0; nt<4; ++nt)
        acc[mt][nt] = __builtin_amdgcn_mfma_f32_16x16x32_bf16(af[mt].bf, bfg[nt].bf, acc[mt][nt], 0, 0, 0);
  }

  #pragma unroll
  for (int mt=0; mt<4; ++mt){
    #pragma unroll
    for (int nt=0; nt<4; ++nt){
      const int col = N0 + wn*64 + nt*16 + lo;
      const int dir = col >> 9, n = col & 511;
      const float bv = bias[col];
      const int wS = (n >> 4) & 7;               // scan wave
      const int qS = (n >> 2) & 3;               // scan quad
      const int sS = ((n >> 7) << 2) + (n & 3);  // scan slot
      #pragma unroll
      for (int r=0; r<4; ++r){
        const int row = M0 + wm*64 + mt*16 + quad*4 + r;
        const int t = row >> 6, b = row & 63;
        const int bid = dir*4 + (b >> 4);
        const int lS = qS*16 + (b & 15);
        const size_t o = ((((size_t)bid*TT + t)*8 + wS)*64 + lS)*16 + sS;
        xp[o] = f2bf(acc[mt][nt][r] + bv);
      }
    }
  }
}

// ---------------- BiLSTM scan ----------------
// 8 WGs: bid = dir*4 + bg; each WG: 16 sequences, 512 steps.
// Per step: D[gate 512][batch 16] = W(512x128) * h(128x16), MFMA 16x16x32 bf16.
// Unroll x4: static 4-phase rotation of prefetch regs (depth-4) and store-data
// regs so forced vmcnt waits (store-source WAR, load RAW) reference VMEM ops
// >= 4 steps old. lgkm-only barrier keeps VMEM off the critical path.

__global__ __launch_bounds__(512) void k_scan(
    const float* __restrict__ w_hh,          // [2][512][128]
    const unsigned short* __restrict__ xp,   // [bid][t][w][lane][16] bf16
    unsigned short* __restrict__ xout)       // [t][64][256] bf16
{
  const int bid = blockIdx.x;           // 0..7
  const int dir = bid >> 2, bg = bid & 3;
  const int tid = threadIdx.x;
  const int l = tid & 63, w = tid >> 6;
  const int quad = l >> 4, lo = l & 15;

  // static weight A-frags: A[m=lo within tile][k=quad*8+j], pre-scaled per gate
  FragU afr[4][4];
  {
    const float* wb = w_hh + (size_t)dir*G4*HH;
    #pragma unroll
    for (int g=0; g<4; ++g){
      const float s = (g == 2) ? SC_TANH : SC_SIG;
      const int m = g*HH + w*16 + lo;
      #pragma unroll
      for (int kq=0; kq<4; ++kq){
        const float* p = wb + (size_t)m*HH + kq*32 + quad*8;
        #pragma unroll
        for (int j=0; j<8; ++j) afr[g][kq].us[j] = f2bf(p[j] * s);
      }
    }
  }

  __shared__ __align__(16) unsigned short hbuf[2][16][136];  // [buf][batch][k], +8 pad
  for (int i = tid; i < 2*16*136; i += 512) ((unsigned short*)hbuf)[i] = 0;
  __syncthreads();

  float c[4] = {0.f,0.f,0.f,0.f};
  const int t0 = dir ? (TT-1) : 0;
  const int dt = dir ? -1 : 1;
  const int dirOff = dir * HH;
  const int jbase = w*16 + quad*4;
  const unsigned short* xpb = xp + ((size_t)bid*TT*8 + w)*1024 + l*16;

  // depth-4 register prefetch of xp (32 B/lane, 2x dwordx4)
  PF2 pf[4];
  #pragma unroll
  for (int k=0; k<4; ++k){
    const unsigned short* p = xpb + (size_t)(t0 + dt*k)*8192;
    pf[k].v[0] = *(const u32x4*)p;
    pf[k].v[1] = *(const u32x4*)(p + 8);
  }

  for (int ob=0; ob<TT/4; ++ob){
    #pragma unroll
    for (int ph=0; ph<4; ++ph){
      const int it = ob*4 + ph;
      const int t = t0 + dt*it;
      const int rb = ph & 1;          // read h buffer (starts at 0)
      const int wb2 = rb ^ 1;         // write h buffer

      // acc init = xp (bias + activation scale already folded in)
      f32x4 acc[4];
      #pragma unroll
      for (int g=0; g<4; ++g)
        #pragma unroll
        for (int r=0; r<4; ++r) acc[g][r] = bf2f(pf[ph].us[g*4+r]);

      // reload this phase's prefetch regs for step it+4
      {
        const int itp = (it+4 < TT) ? (it+4) : (TT-1);
        const unsigned short* p = xpb + (size_t)(t0 + dt*itp)*8192;
        pf[ph].v[0] = *(const u32x4*)p;
        pf[ph].v[1] = *(const u32x4*)(p + 8);
      }

      // B-frags: B[k][n=batch] = h[batch][k]
      FragU bfr[4];
      #pragma unroll
      for (int kq=0; kq<4; ++kq)
        bfr[kq].u4 = *(const u32x4*)&hbuf[rb][lo][kq*32 + quad*8];

      #pragma unroll
      for (int kq=0; kq<4; ++kq)
        #pragma unroll
        for (int g=0; g<4; ++g)
          acc[g] = __builtin_amdgcn_mfma_f32_16x16x32_bf16(afr[g][kq].bf, bfr[kq].bf, acc[g], 0, 0, 0);

      // epilogue: lane has unit (j = jbase+r, batch = lo); yi/yf/yg/yo pre-scaled
      unsigned hu[4];
      #pragma unroll
      for (int r=0; r<4; ++r){
        float si = rsig(acc[0][r]);
        float sf = rsig(acc[1][r]);
        float tg = __builtin_fmaf(2.0f, rsig(acc[2][r]), -1.0f);
        float so = rsig(acc[3][r]);
        float ct = __builtin_fmaf(sf, c[r], si*tg);
        c[r] = ct;
        float tc = __builtin_fmaf(2.0f, rsig(SC_TANH*ct), -1.0f);
        hu[r] = __builtin_bit_cast(unsigned, so*tc) + 0x8000u;
      }
      u32x2 hv;
      hv.x = (hu[0] >> 16) | (hu[1] & 0xFFFF0000u);
      hv.y = (hu[2] >> 16) | (hu[3] & 0xFFFF0000u);
      *(u32x2*)&hbuf[wb2][lo][jbase] = hv;
      *(u32x2*)(xout + (((size_t)t*NB) + bg*16 + lo)*HDIM + dirOff + jbase) = hv;

      // raw barrier: wait LDS only — no vmcnt drain of prefetch loads / xout stores
      asm volatile("s_waitcnt lgkmcnt(0)\n\ts_barrier" ::: "memory");
    }
  }
}

// ---------------- emission GEMM: em[b][t][l] = x2 row . w_out[l] + b_out[l] ----------------

__global__ __launch_bounds__(256) void k_em(
    const unsigned short* __restrict__ x2,  // [32768][256] bf16
    const float* __restrict__ w_out,        // [9][256]
    const float* __restrict__ b_out,        // [9]
    float* __restrict__ em)                 // [64][512][9]
{
  const int tid = threadIdx.x;
  const int l = tid & 63, w = tid >> 6;
  const int quad = l >> 4, lo = l & 15;
  const int M0 = blockIdx.x*128 + w*32;

  FragU bf[8];
  #pragma unroll
  for (int kq=0; kq<8; ++kq){
    #pragma unroll
    for (int j=0; j<8; ++j){
      float v = (lo < 9) ? w_out[lo*HDIM + kq*32 + quad*8 + j] : 0.f;
      bf[kq].us[j] = f2bf(v);
    }
  }

  f32x4 acc[2] = {};
  #pragma unroll
  for (int kq=0; kq<8; ++kq){
    FragU a0, a1;
    a0.u4 = *(const u32x4*)(x2 + ((size_t)(M0 + lo))*HDIM + kq*32 + quad*8);
    a1.u4 = *(const u32x4*)(x2 + ((size_t)(M0 + 16 + lo))*HDIM + kq*32 + quad*8);
    acc[0] = __builtin_amdgcn_mfma_f32_16x16x32_bf16(a0.bf, bf[kq].bf, acc[0], 0, 0, 0);
    acc[1] = __builtin_amdgcn_mfma_f32_16x16x32_bf16(a1.bf, bf[kq].bf, acc[1], 0, 0, 0);
  }

  if (lo < 9){
    const float bo = b_out[lo];
    #pragma unroll
    for (int mt=0; mt<2; ++mt){
      #pragma unroll
      for (int r=0; r<4; ++r){
        const int row = M0 + mt*16 + quad*4 + r;
        const int t = row >> 6, b = row & 63;
        em[((size_t)b*TT + t)*9 + lo] = acc[mt][r] + bo;
      }
    }
  }
}

// ---------------- CRF: log-semiring matrix tree reduction ----------------

__global__ __launch_bounds__(256) void k_crf_build(
    const int* __restrict__ word, const float* __restrict__ em,
    const float* __restrict__ start_t, const float* __restrict__ trans,
    float* __restrict__ G0)                 // [64][512][81]
{
  int id = blockIdx.x*256 + threadIdx.x;    // < 64*512*81
  int b = id / (TT*81);
  int rem = id - b*(TT*81);
  int t = rem / 81;
  int ij = rem - t*81;
  int i = ij / 9, j = ij - i*9;
  float e = em[((size_t)b*TT + t)*9 + j];
  float v;
  if (t == 0) v = start_t[j] + e;                       // row-independent
  else if (word[b*TT + t] > 0) v = trans[i*9 + j] + e;
  else v = (i == j) ? 0.f : -1e30f;                     // LSE-identity
  G0[(size_t)id] = v;
}

// dst = radix-8 LSE-matmul reduction of src groups (order-preserving)
__global__ __launch_bounds__(128) void k_crf_reduce(
    const float* __restrict__ src, float* __restrict__ dst, const int nm)
{
  const int bid = blockIdx.x;
  const int ng = nm >> 3;
  const int b = bid / ng, g = bid - b*ng;
  const int tid = threadIdx.x;
  __shared__ float R[2][81];
  const float* base = src + ((size_t)b*nm + g*8)*81;
  if (tid < 81) R[0][tid] = base[tid];
  int cur = 0;
  for (int s=1; s<8; ++s){
    __syncthreads();
    if (tid < 81){
      int i = tid/9, j = tid - (tid/9)*9;
      const float* M = base + (size_t)s*81;
      float a[9], mx = -3.0e38f;
      #pragma unroll
      for (int k=0;k<9;++k){ a[k] = R[cur][i*9+k] + M[k*9+j]; mx = fmaxf(mx, a[k]); }
      float sm = 0.f;
      #pragma unroll
      for (int k=0;k<9;++k) sm += __expf(a[k]-mx);
      R[cur^1][tid] = mx + __logf(sm);
    }
    cur ^= 1;
  }
  __syncthreads();
  if (tid < 81) dst[((size_t)b*ng + g)*81 + tid] = R[cur][tid];
}

__global__ __launch_bounds__(256) void k_crf_num(
    const int* __restrict__ word, const int* __restrict__ label,
    const float* __restrict__ em, const float* __restrict__ start_t,
    const float* __restrict__ end_t, const float* __restrict__ trans,
    float* __restrict__ numv)
{
  const int b = blockIdx.x, tid = threadIdx.x;
  __shared__ float sred[256];
  __shared__ int ssend;
  int ms = 0;
  for (int t=tid; t<TT; t+=256) ms += (word[b*TT+t] > 0) ? 1 : 0;
  sred[tid] = (float)ms;
  __syncthreads();
  for (int st=128; st>0; st>>=1){ if (tid<st) sred[tid] += sred[tid+st]; __syncthreads(); }
  if (tid==0) ssend = (int)sred[0] - 1;
  __syncthreads();
  const int send = ssend;
  float part = 0.f;
  for (int t=tid; t<TT; t+=256){
    int tag = label[b*TT+t];
    float es = em[((size_t)b*TT+t)*9 + tag];
    if (t == 0) part += start_t[tag] + es;
    else if (word[b*TT+t] > 0) part += trans[label[b*TT+t-1]*9 + tag] + es;
    if (t == send) part += end_t[tag];
  }
  __syncthreads();
  sred[tid] = part;
  __syncthreads();
  for (int st=128; st>0; st>>=1){ if (tid<st) sred[tid] += sred[tid+st]; __syncthreads(); }
  if (tid==0) numv[b] = sred[0];
}

__global__ __launch_bounds__(64) void k_final(
    const float* __restrict__ numv, const float* __restrict__ G3,
    const float* __restrict__ end_t, float* __restrict__ out)
{
  const int b = threadIdx.x;  // 0..63
  float a[9], mx = -3.0e38f;
  #pragma unroll
  for (int j=0;j<9;++j){ a[j] = G3[b*81 + j] + end_t[j]; mx = fmaxf(mx, a[j]); }
  float sm = 0.f;
  #pragma unroll
  for (int j=0;j<9;++j) sm += __expf(a[j]-mx);
  float denom = mx + __logf(sm);
  float v = numv[b] - denom;
  #pragma unroll
  for (int off=32; off>0; off>>=1) v += __shfl_down(v, off, 64);
  if (b == 0) out[0] = -v;
}

// ---------------- launch ----------------

extern "C" void kernel_launch(void* const* d_in, const int* in_sizes, int n_in,
                              void* d_out, int out_size, void* d_ws, size_t ws_size,
                              hipStream_t stream)
{
  (void)in_sizes; (void)n_in; (void)out_size; (void)ws_size;
  const int*   word  = (const int*)d_in[0];
  const int*   label = (const int*)d_in[1];
  const float* emb   = (const float*)d_in[2];
  const float* w_ih0 = (const float*)d_in[3];
  const float* w_hh0 = (const float*)d_in[4];
  const float* b_ih0 = (const float*)d_in[5];
  const float* b_hh0 = (const float*)d_in[6];
  const float* w_ih1 = (const float*)d_in[7];
  const float* w_hh1 = (const float*)d_in[8];
  const float* b_ih1 = (const float*)d_in[9];
  const float* b_hh1 = (const float*)d_in[10];
  const float* w_out = (const float*)d_in[11];
  const float* b_out = (const float*)d_in[12];
  const float* start_t = (const float*)d_in[13];
  const float* end_t   = (const float*)d_in[14];
  const float* trans   = (const float*)d_in[15];

  char* ws = (char*)d_ws;
  unsigned short* xp    = (unsigned short*)(ws + 0);            // 67108864 B
  unsigned short* xe    = (unsigned short*)(ws + 67108864);     // 20971520 B (dead after gemm0)
  float*          G0    = (float*)(ws + 67108864);              // overlay on xe (10616832 B)
  unsigned short* x1    = (unsigned short*)(ws + 88080384);     // 16777216 B
  unsigned short* x2    = (unsigned short*)(ws + 104857600);    // 16777216 B
  unsigned short* Bp0   = (unsigned short*)(ws + 121634816);    // 655360 B
  unsigned short* Bp1   = (unsigned short*)(ws + 122290176);    // 524288 B
  float*          bias0 = (float*)(ws + 122814464);             // 4096 B
  float*          bias1 = (float*)(ws + 122818560);             // 4096 B
  float*          em    = (float*)(ws + 122822656);             // 1179648 B
  float*          G1    = (float*)(ws + 124002304);             // 1327104 B
  float*          G2    = (float*)(ws + 125329408);             // 165888 B
  float*          G3    = (float*)(ws + 125495296);             // 20736 B
  float*          numv  = (float*)(ws + 125516032);             // 256 B

  hipLaunchKernelGGL(k_prep_bias, dim3(8), dim3(256), 0, stream, b_ih0, b_hh0, b_ih1, b_hh1, bias0, bias1);
  hipLaunchKernelGGL(k_prep_b, dim3(1280), dim3(256), 0, stream, w_ih0, Bp0, 300, 320);
  hipLaunchKernelGGL(k_prep_b, dim3(1024), dim3(256), 0, stream, w_ih1, Bp1, 256, 256);
  hipLaunchKernelGGL(k_embed, dim3(32768), dim3(320), 0, stream, word, emb, xe);
  hipLaunchKernelGGL(k_gemm, dim3(256, 8), dim3(256), 0, stream, xe, Bp0, bias0, xp, 320, 10);
  hipLaunchKernelGGL(k_scan, dim3(8), dim3(512), 0, stream, w_hh0, xp, x1);
  hipLaunchKernelGGL(k_gemm, dim3(256, 8), dim3(256), 0, stream, x1, Bp1, bias1, xp, 256, 8);
  hipLaunchKernelGGL(k_scan, dim3(8), dim3(512), 0, stream, w_hh1, xp, x2);
  hipLaunchKernelGGL(k_em, dim3(256), dim3(256), 0, stream, x2, w_out, b_out, em);
  hipLaunchKernelGGL(k_crf_build, dim3(10368), dim3(256), 0, stream, word, em, start_t, trans, G0);
  hipLaunchKernelGGL(k_crf_reduce, dim3(4096), dim3(128), 0, stream, G0, G1, 512);
  hipLaunchKernelGGL(k_crf_reduce, dim3(512), dim3(128), 0, stream, G1, G2, 64);
  hipLaunchKernelGGL(k_crf_reduce, dim3(64), dim3(128), 0, stream, G2, G3, 8);
  hipLaunchKernelGGL(k_crf_num, dim3(64), dim3(256), 0, stream, word, label, em, start_t, end_t, trans, numv);
  hipLaunchKernelGGL(k_final, dim3(1), dim3(64), 0, stream, numv, G3, end_t, (float*)d_out);
}

// Round 4
// 1143.767 us; speedup vs baseline: 1.7616x; 1.0323x over previous
//
#include <hip/hip_runtime.h>

#define TT 512
#define NB 64
#define HH 128
#define G4 512
#define HDIM 256

typedef __bf16 bf16x8 __attribute__((ext_vector_type(8)));
typedef float f32x4 __attribute__((ext_vector_type(4)));
typedef unsigned int u32x4 __attribute__((ext_vector_type(4)));

union FragU { u32x4 u4; bf16x8 bf; unsigned short us[8]; };

#define SC_SIG  -1.442695041f   // fold: sigma(x) = rcp(1 + exp2(-log2e * x))
#define SC_TANH -2.885390082f   // fold: tanh(x)  = 2*rcp(1 + exp2(-2log2e * x)) - 1

__device__ __forceinline__ unsigned short f2bf(float f){
  unsigned u = __builtin_bit_cast(unsigned, f);
  return (unsigned short)((u + 0x7FFFu + ((u>>16)&1u)) >> 16);
}
__device__ __forceinline__ float bf2f(unsigned short h){
  unsigned u = ((unsigned)h) << 16;
  return __builtin_bit_cast(float, u);
}
// y is pre-scaled by SC_SIG (or SC_TANH): returns sigma
__device__ __forceinline__ float rsig(float y){
  return __builtin_amdgcn_rcpf(1.0f + __builtin_amdgcn_exp2f(y));
}

// ---------------- merged prep: biases + both Bp weight repacks ----------------

__global__ __launch_bounds__(256) void k_prep(
    const float* __restrict__ bi0, const float* __restrict__ bh0,
    const float* __restrict__ bi1, const float* __restrict__ bh1,
    const float* __restrict__ w_ih0, const float* __restrict__ w_ih1,
    float* __restrict__ bias0, float* __restrict__ bias1,
    unsigned short* __restrict__ Bp0, unsigned short* __restrict__ Bp1)
{
  int id = blockIdx.x*256 + threadIdx.x;
  if (id < 2048){
    int n = id & 511;
    float s = ((n >> 7) == 2) ? SC_TANH : SC_SIG;
    if (id < 1024) bias0[id] = (bi0[id] + bh0[id]) * s;
    else { int k = id - 1024; bias1[k] = (bi1[k] + bh1[k]) * s; }
    return;
  }
  id -= 2048;
  if (id < 320*1024){
    int k = id >> 10, c = id & 1023;
    int dir = c >> 9, n = c & 511;
    float s = ((n >> 7) == 2) ? SC_TANH : SC_SIG;
    float v = (k < 300) ? w_ih0[((size_t)(dir*512 + n))*300 + k] * s : 0.f;
    Bp0[(((size_t)(k>>3))*1024 + c)*8 + (k&7)] = f2bf(v);
    return;
  }
  id -= 320*1024;
  if (id < 256*1024){
    int k = id >> 10, c = id & 1023;
    int dir = c >> 9, n = c & 511;
    float s = ((n >> 7) == 2) ? SC_TANH : SC_SIG;
    float v = w_ih1[((size_t)(dir*512 + n))*256 + k] * s;
    Bp1[(((size_t)(k>>3))*1024 + c)*8 + (k&7)] = f2bf(v);
  }
}

// x_emb[row][c] bf16, row = t*64+b, padded to 320 cols
__global__ __launch_bounds__(320) void k_embed(
    const int* __restrict__ word, const float* __restrict__ emb,
    unsigned short* __restrict__ xe)
{
  int row = blockIdx.x;       // 0..32767
  int c = threadIdx.x;        // 0..319
  int t = row >> 6, b = row & 63;
  int wd = word[b*TT + t];
  float v = (c < 300) ? emb[(size_t)wd*300 + c] : 0.f;
  xe[(size_t)row*320 + c] = f2bf(v);
}

// ---------------- input GEMM: xp = A(32768 x K) * Bp(K x 1024) + bias ----------------
// output scattered to xp[bid16][t][w][lane64][8] bf16 (scan post-repack order)

__global__ __launch_bounds__(256) void k_gemm(
    const unsigned short* __restrict__ A,   // [32768][lda] bf16
    const unsigned short* __restrict__ Bp,  // [K/8][1024][8] bf16
    const float* __restrict__ bias,         // [1024]
    unsigned short* __restrict__ xp,
    const int lda, const int KB)
{
  const int tid = threadIdx.x;
  const int l = tid & 63, w = tid >> 6;
  const int quad = l >> 4, lo = l & 15;
  const int wm = w >> 1, wn = w & 1;
  const int M0 = blockIdx.x * 128;
  const int N0 = blockIdx.y * 128;

  __shared__ __align__(16) unsigned short Asl[4*128*8];  // [q][m][8]
  __shared__ __align__(16) unsigned short Bsl[4*128*8];  // [q][n][8]

  f32x4 acc[4][4] = {};

  for (int kb=0; kb<KB; ++kb){
    const int k0 = kb*32;
    u32x4 va[2], vb[2];
    #pragma unroll
    for (int hh=0; hh<2; ++hh){
      const int cch = tid + hh*256;
      const int q = cch >> 7, mm = cch & 127;
      va[hh] = *(const u32x4*)(A + (size_t)(M0+mm)*lda + k0 + q*8);
      vb[hh] = *(const u32x4*)(Bp + (((size_t)((k0>>3)+q))*1024 + N0 + mm)*8);
    }
    __syncthreads();   // WAR vs previous iteration's frag reads
    #pragma unroll
    for (int hh=0; hh<2; ++hh){
      const int cch = tid + hh*256;
      *(u32x4*)&Asl[cch*8] = va[hh];
      *(u32x4*)&Bsl[cch*8] = vb[hh];
    }
    __syncthreads();

    FragU af[4], bfg[4];
    #pragma unroll
    for (int mt=0; mt<4; ++mt)
      af[mt].u4 = *(const u32x4*)&Asl[((quad<<7) + wm*64 + mt*16 + lo)*8];
    #pragma unroll
    for (int nt=0; nt<4; ++nt)
      bfg[nt].u4 = *(const u32x4*)&Bsl[((quad<<7) + wn*64 + nt*16 + lo)*8];
    #pragma unroll
    for (int mt=0; mt<4; ++mt)
      #pragma unroll
      for (int nt=0; nt<4; ++nt)
        acc[mt][nt] = __builtin_amdgcn_mfma_f32_16x16x32_bf16(af[mt].bf, bfg[nt].bf, acc[mt][nt], 0, 0, 0);
  }

  #pragma unroll
  for (int mt=0; mt<4; ++mt){
    #pragma unroll
    for (int nt=0; nt<4; ++nt){
      const int col = N0 + wn*64 + nt*16 + lo;
      const int dir = col >> 9, n = col & 511;
      const float bv = bias[col];
      const int g  = n >> 7;                 // gate type
      const int j  = n & 127;                // unit
      const int wS = j >> 4;                 // scan wave
      const int qS = (j >> 2) & 3;           // scan quad
      const int hS = (j >> 1) & 1;           // scan hi-half
      const int uS = j & 1;                  // scan unit-slot
      const int idx8 = g*2 + uS;
      #pragma unroll
      for (int r=0; r<4; ++r){
        const int row = M0 + wm*64 + mt*16 + quad*4 + r;
        const int t = row >> 6, b = row & 63;
        const int bidS = dir*8 + (b >> 3);
        const int lS = qS*16 + hS*8 + (b & 7);
        const size_t o = ((((size_t)bidS*TT + t)*8 + wS)*64 + lS)*8 + idx8;
        xp[o] = f2bf(acc[mt][nt][r] + bv);
      }
    }
  }
}

// ---------------- BiLSTM scan ----------------
// 16 WGs: bid = dir*8 + bg; each WG: 8 sequences, 512 steps, 8 waves.
// Per step: D[gate 512][16] = W(512x128) * h(128x16) with B cols 8..15 = zero
// rows of hbuf. Post-MFMA repack via shfl_xor(8): every lane gets 2 valid
// units -> epilogue VALU per CU halves vs Nb=16. xp pre-scattered to the
// post-repack per-lane order (16 B/lane/step, depth-4 register prefetch).
// lgkm-only barrier keeps VMEM off the per-step critical path.

__global__ __launch_bounds__(512) void k_scan(
    const float* __restrict__ w_hh,          // [2][512][128]
    const unsigned short* __restrict__ xp,   // [bid][t][w][lane][8] bf16
    unsigned short* __restrict__ xout)       // [t][64][256] bf16
{
  const int bid = blockIdx.x;           // 0..15
  const int dir = bid >> 3, bg = bid & 7;
  const int tid = threadIdx.x;
  const int l = tid & 63, w = tid >> 6;
  const int quad = l >> 4, lo = l & 15;
  const int hi = lo >> 3, bb = lo & 7;

  // static weight A-frags: A[m=lo within tile][k=quad*8+j], pre-scaled per gate
  FragU afr[4][4];
  {
    const float* wb = w_hh + (size_t)dir*G4*HH;
    #pragma unroll
    for (int g=0; g<4; ++g){
      const float s = (g == 2) ? SC_TANH : SC_SIG;
      const int m = g*HH + w*16 + lo;
      #pragma unroll
      for (int kq=0; kq<4; ++kq){
        const float* p = wb + (size_t)m*HH + kq*32 + quad*8;
        #pragma unroll
        for (int j=0; j<8; ++j) afr[g][kq].us[j] = f2bf(p[j] * s);
      }
    }
  }

  __shared__ __align__(16) unsigned short hbuf[2][16][136];  // rows 8-15 stay zero
  for (int i = tid; i < 2*16*136; i += 512) ((unsigned short*)hbuf)[i] = 0;
  __syncthreads();

  float c0 = 0.f, c1 = 0.f;
  const int t0 = dir ? (TT-1) : 0;
  const int dt = dir ? -1 : 1;
  const int dirOff = dir * HH;
  const int jj0 = w*16 + quad*4 + hi*2;    // first unit of this lane (post-repack)
  const unsigned short* xpb = xp + ((size_t)bid*TT*8 + w)*512 + l*8;
  // per-step stride = 8*64*8 = 4096 shorts

  // depth-4 register prefetch of xp (16 B/lane, 1x dwordx4)
  u32x4 pf[4];
  #pragma unroll
  for (int k=0; k<4; ++k)
    pf[k] = *(const u32x4*)(xpb + (size_t)(t0 + dt*k)*4096);

  for (int ob=0; ob<TT/4; ++ob){
    #pragma unroll
    for (int ph=0; ph<4; ++ph){
      const int it = ob*4 + ph;
      const int t = t0 + dt*it;
      const int rb = ph & 1;          // read h buffer (starts at 0)
      const int wb2 = rb ^ 1;         // write h buffer

      // B-frags: B[k][n=batch] = h[batch][k]; rows 8-15 are zero
      FragU bfr[4];
      #pragma unroll
      for (int kq=0; kq<4; ++kq)
        bfr[kq].u4 = *(const u32x4*)&hbuf[rb][lo][kq*32 + quad*8];

      f32x4 acc[4] = {};
      #pragma unroll
      for (int kq=0; kq<4; ++kq)
        #pragma unroll
        for (int g=0; g<4; ++g)
          acc[g] = __builtin_amdgcn_mfma_f32_16x16x32_bf16(afr[g][kq].bf, bfr[kq].bf, acc[g], 0, 0, 0);

      // consume this phase's xp, then reload it for step it+4
      FragU xs; xs.u4 = pf[ph];
      {
        const int itp = (it+4 < TT) ? (it+4) : (TT-1);
        pf[ph] = *(const u32x4*)(xpb + (size_t)(t0 + dt*itp)*4096);
      }

      // repack: lanes hi=1 take rows r=2,3 from partner lane (lo-8);
      // after this every lane owns units jj0, jj0+1 for batch bb.
      float gv0[4], gv1[4];
      #pragma unroll
      for (int g=0; g<4; ++g){
        float s2 = __shfl_xor(acc[g][2], 8, 64);
        float s3 = __shfl_xor(acc[g][3], 8, 64);
        float u0 = hi ? s2 : acc[g][0];
        float u1 = hi ? s3 : acc[g][1];
        gv0[g] = u0 + bf2f(xs.us[g*2+0]);
        gv1[g] = u1 + bf2f(xs.us[g*2+1]);
      }

      // epilogue: 2 units per lane (pre-scaled gate values)
      float si0 = rsig(gv0[0]), sf0 = rsig(gv0[1]);
      float tg0 = __builtin_fmaf(2.0f, rsig(gv0[2]), -1.0f);
      float so0 = rsig(gv0[3]);
      c0 = __builtin_fmaf(sf0, c0, si0*tg0);
      float h0 = so0 * __builtin_fmaf(2.0f, rsig(SC_TANH*c0), -1.0f);

      float si1 = rsig(gv1[0]), sf1 = rsig(gv1[1]);
      float tg1 = __builtin_fmaf(2.0f, rsig(gv1[2]), -1.0f);
      float so1 = rsig(gv1[3]);
      c1 = __builtin_fmaf(sf1, c1, si1*tg1);
      float h1 = so1 * __builtin_fmaf(2.0f, rsig(SC_TANH*c1), -1.0f);

      unsigned hu0 = __builtin_bit_cast(unsigned, h0) + 0x8000u;
      unsigned hu1 = __builtin_bit_cast(unsigned, h1) + 0x8000u;
      unsigned hv = (hu0 >> 16) | (hu1 & 0xFFFF0000u);
      *(unsigned*)&hbuf[wb2][bb][jj0] = hv;
      *(unsigned*)(xout + ((size_t)t*NB + bg*8 + bb)*HDIM + dirOff + jj0) = hv;

      // raw barrier: wait LDS only — no vmcnt drain of prefetch loads / stores
      asm volatile("s_waitcnt lgkmcnt(0)\n\ts_barrier" ::: "memory");
    }
  }
}

// ---------------- emission GEMM: em[b][t][l] = x2 row . w_out[l] + b_out[l] ----------------

__global__ __launch_bounds__(256) void k_em(
    const unsigned short* __restrict__ x2,  // [32768][256] bf16
    const float* __restrict__ w_out,        // [9][256]
    const float* __restrict__ b_out,        // [9]
    float* __restrict__ em)                 // [64][512][9]
{
  const int tid = threadIdx.x;
  const int l = tid & 63, w = tid >> 6;
  const int quad = l >> 4, lo = l & 15;
  const int M0 = blockIdx.x*128 + w*32;

  FragU bf[8];
  #pragma unroll
  for (int kq=0; kq<8; ++kq){
    #pragma unroll
    for (int j=0; j<8; ++j){
      float v = (lo < 9) ? w_out[lo*HDIM + kq*32 + quad*8 + j] : 0.f;
      bf[kq].us[j] = f2bf(v);
    }
  }

  f32x4 acc[2] = {};
  #pragma unroll
  for (int kq=0; kq<8; ++kq){
    FragU a0, a1;
    a0.u4 = *(const u32x4*)(x2 + ((size_t)(M0 + lo))*HDIM + kq*32 + quad*8);
    a1.u4 = *(const u32x4*)(x2 + ((size_t)(M0 + 16 + lo))*HDIM + kq*32 + quad*8);
    acc[0] = __builtin_amdgcn_mfma_f32_16x16x32_bf16(a0.bf, bf[kq].bf, acc[0], 0, 0, 0);
    acc[1] = __builtin_amdgcn_mfma_f32_16x16x32_bf16(a1.bf, bf[kq].bf, acc[1], 0, 0, 0);
  }

  if (lo < 9){
    const float bo = b_out[lo];
    #pragma unroll
    for (int mt=0; mt<2; ++mt){
      #pragma unroll
      for (int r=0; r<4; ++r){
        const int row = M0 + mt*16 + quad*4 + r;
        const int t = row >> 6, b = row & 63;
        em[((size_t)b*TT + t)*9 + lo] = acc[mt][r] + bo;
      }
    }
  }
}

// ---------------- CRF: fused build + radix-8 LSE-matmul reduction ----------------
// Stage 1 builds the 9x9 transition matrices from em/word/trans on the fly
// (no 170 MB G0 materialization) and reduces 8 timesteps -> 1 matrix.

__global__ __launch_bounds__(128) void k_crf_r1f(
    const int* __restrict__ word, const float* __restrict__ em,
    const float* __restrict__ start_t, const float* __restrict__ trans,
    float* __restrict__ dst)                // [64][64][81]
{
  const int bid = blockIdx.x;       // 64*64
  const int b = bid >> 6, g = bid & 63;
  const int tid = threadIdx.x;
  const int t0 = g*8;
  __shared__ float R[2][81];
  __shared__ float emsh[8][9];
  __shared__ int wsh[8];
  if (tid < 72){
    int s = tid/9, j = tid - (tid/9)*9;
    emsh[s][j] = em[((size_t)b*TT + t0+s)*9 + j];
  }
  if (tid < 8) wsh[tid] = word[b*TT + t0 + tid];
  __syncthreads();
  int i=0, j=0; float tr[9];
  if (tid < 81){
    i = tid/9; j = tid - i*9;
    #pragma unroll
    for (int k=0;k<9;++k) tr[k] = trans[k*9+j];   // trans[i][j] = tr[i]
    float v;
    if (t0 == 0) v = start_t[j] + emsh[0][j];
    else if (wsh[0] > 0) v = tr[i] + emsh[0][j];
    else v = (i==j) ? 0.f : -1e30f;
    R[0][tid] = v;
  }
  int cur = 0;
  for (int s=1; s<8; ++s){
    __syncthreads();
    if (tid < 81){
      if (wsh[s] > 0){
        float a[9], mx = -3.0e38f;
        #pragma unroll
        for (int k=0;k<9;++k){ a[k] = R[cur][i*9+k] + tr[k]; mx = fmaxf(mx, a[k]); }
        float sm = 0.f;
        #pragma unroll
        for (int k=0;k<9;++k) sm += __expf(a[k]-mx);
        R[cur^1][tid] = mx + __logf(sm) + emsh[s][j];
      } else {
        R[cur^1][tid] = R[cur][tid];
      }
    }
    cur ^= 1;
  }
  __syncthreads();
  if (tid < 81) dst[((size_t)bid)*81 + tid] = R[cur][tid];
}

// dst = radix-8 LSE-matmul reduction of src groups (order-preserving)
__global__ __launch_bounds__(128) void k_crf_reduce(
    const float* __restrict__ src, float* __restrict__ dst, const int nm)
{
  const int bid = blockIdx.x;
  const int ng = nm >> 3;
  const int b = bid / ng, g = bid - b*ng;
  const int tid = threadIdx.x;
  __shared__ float R[2][81];
  const float* base = src + ((size_t)b*nm + g*8)*81;
  if (tid < 81) R[0][tid] = base[tid];
  int cur = 0;
  for (int s=1; s<8; ++s){
    __syncthreads();
    if (tid < 81){
      int i = tid/9, j = tid - (tid/9)*9;
      const float* M = base + (size_t)s*81;
      float a[9], mx = -3.0e38f;
      #pragma unroll
      for (int k=0;k<9;++k){ a[k] = R[cur][i*9+k] + M[k*9+j]; mx = fmaxf(mx, a[k]); }
      float sm = 0.f;
      #pragma unroll
      for (int k=0;k<9;++k) sm += __expf(a[k]-mx);
      R[cur^1][tid] = mx + __logf(sm);
    }
    cur ^= 1;
  }
  __syncthreads();
  if (tid < 81) dst[((size_t)b*ng + g)*81 + tid] = R[cur][tid];
}

__global__ __launch_bounds__(256) void k_crf_num(
    const int* __restrict__ word, const int* __restrict__ label,
    const float* __restrict__ em, const float* __restrict__ start_t,
    const float* __restrict__ end_t, const float* __restrict__ trans,
    float* __restrict__ numv)
{
  const int b = blockIdx.x, tid = threadIdx.x;
  __shared__ float sred[256];
  __shared__ int ssend;
  int ms = 0;
  for (int t=tid; t<TT; t+=256) ms += (word[b*TT+t] > 0) ? 1 : 0;
  sred[tid] = (float)ms;
  __syncthreads();
  for (int st=128; st>0; st>>=1){ if (tid<st) sred[tid] += sred[tid+st]; __syncthreads(); }
  if (tid==0) ssend = (int)sred[0] - 1;
  __syncthreads();
  const int send = ssend;
  float part = 0.f;
  for (int t=tid; t<TT; t+=256){
    int tag = label[b*TT+t];
    float es = em[((size_t)b*TT+t)*9 + tag];
    if (t == 0) part += start_t[tag] + es;
    else if (word[b*TT+t] > 0) part += trans[label[b*TT+t-1]*9 + tag] + es;
    if (t == send) part += end_t[tag];
  }
  __syncthreads();
  sred[tid] = part;
  __syncthreads();
  for (int st=128; st>0; st>>=1){ if (tid<st) sred[tid] += sred[tid+st]; __syncthreads(); }
  if (tid==0) numv[b] = sred[0];
}

__global__ __launch_bounds__(64) void k_final(
    const float* __restrict__ numv, const float* __restrict__ G3,
    const float* __restrict__ end_t, float* __restrict__ out)
{
  const int b = threadIdx.x;  // 0..63
  float a[9], mx = -3.0e38f;
  #pragma unroll
  for (int j=0;j<9;++j){ a[j] = G3[b*81 + j] + end_t[j]; mx = fmaxf(mx, a[j]); }
  float sm = 0.f;
  #pragma unroll
  for (int j=0;j<9;++j) sm += __expf(a[j]-mx);
  float denom = mx + __logf(sm);
  float v = numv[b] - denom;
  #pragma unroll
  for (int off=32; off>0; off>>=1) v += __shfl_down(v, off, 64);
  if (b == 0) out[0] = -v;
}

// ---------------- launch ----------------

extern "C" void kernel_launch(void* const* d_in, const int* in_sizes, int n_in,
                              void* d_out, int out_size, void* d_ws, size_t ws_size,
                              hipStream_t stream)
{
  (void)in_sizes; (void)n_in; (void)out_size; (void)ws_size;
  const int*   word  = (const int*)d_in[0];
  const int*   label = (const int*)d_in[1];
  const float* emb   = (const float*)d_in[2];
  const float* w_ih0 = (const float*)d_in[3];
  const float* w_hh0 = (const float*)d_in[4];
  const float* b_ih0 = (const float*)d_in[5];
  const float* b_hh0 = (const float*)d_in[6];
  const float* w_ih1 = (const float*)d_in[7];
  const float* w_hh1 = (const float*)d_in[8];
  const float* b_ih1 = (const float*)d_in[9];
  const float* b_hh1 = (const float*)d_in[10];
  const float* w_out = (const float*)d_in[11];
  const float* b_out = (const float*)d_in[12];
  const float* start_t = (const float*)d_in[13];
  const float* end_t   = (const float*)d_in[14];
  const float* trans   = (const float*)d_in[15];

  char* ws = (char*)d_ws;
  unsigned short* xp    = (unsigned short*)(ws + 0);            // 67108864 B
  unsigned short* xe    = (unsigned short*)(ws + 67108864);     // 20971520 B
  unsigned short* x1    = (unsigned short*)(ws + 88080384);     // 16777216 B
  unsigned short* x2    = (unsigned short*)(ws + 104857600);    // 16777216 B
  unsigned short* Bp0   = (unsigned short*)(ws + 121634816);    // 655360 B
  unsigned short* Bp1   = (unsigned short*)(ws + 122290176);    // 524288 B
  float*          bias0 = (float*)(ws + 122814464);             // 4096 B
  float*          bias1 = (float*)(ws + 122818560);             // 4096 B
  float*          em    = (float*)(ws + 122822656);             // 1179648 B
  float*          G1    = (float*)(ws + 124002304);             // 1327104 B
  float*          G2    = (float*)(ws + 125329408);             // 165888 B
  float*          G3    = (float*)(ws + 125495296);             // 20736 B
  float*          numv  = (float*)(ws + 125516032);             // 256 B

  hipLaunchKernelGGL(k_prep, dim3(2312), dim3(256), 0, stream,
                     b_ih0, b_hh0, b_ih1, b_hh1, w_ih0, w_ih1, bias0, bias1, Bp0, Bp1);
  hipLaunchKernelGGL(k_embed, dim3(32768), dim3(320), 0, stream, word, emb, xe);
  hipLaunchKernelGGL(k_gemm, dim3(256, 8), dim3(256), 0, stream, xe, Bp0, bias0, xp, 320, 10);
  hipLaunchKernelGGL(k_scan, dim3(16), dim3(512), 0, stream, w_hh0, xp, x1);
  hipLaunchKernelGGL(k_gemm, dim3(256, 8), dim3(256), 0, stream, x1, Bp1, bias1, xp, 256, 8);
  hipLaunchKernelGGL(k_scan, dim3(16), dim3(512), 0, stream, w_hh1, xp, x2);
  hipLaunchKernelGGL(k_em, dim3(256), dim3(256), 0, stream, x2, w_out, b_out, em);
  hipLaunchKernelGGL(k_crf_r1f, dim3(4096), dim3(128), 0, stream, word, em, start_t, trans, G1);
  hipLaunchKernelGGL(k_crf_reduce, dim3(512), dim3(128), 0, stream, G1, G2, 64);
  hipLaunchKernelGGL(k_crf_reduce, dim3(64), dim3(128), 0, stream, G2, G3, 8);
  hipLaunchKernelGGL(k_crf_num, dim3(64), dim3(256), 0, stream, word, label, em, start_t, end_t, trans, numv);
  hipLaunchKernelGGL(k_final, dim3(1), dim3(64), 0, stream, numv, G3, end_t, (float*)d_out);
}

// Round 5
// 1002.959 us; speedup vs baseline: 2.0089x; 1.1404x over previous
//
#include <hip/hip_runtime.h>

#define TT 512
#define NB 64
#define HH 128
#define G4 512
#define HDIM 256

typedef __bf16 bf16x8 __attribute__((ext_vector_type(8)));
typedef float f32x4 __attribute__((ext_vector_type(4)));
typedef float f32x2 __attribute__((ext_vector_type(2)));
typedef unsigned int u32x4 __attribute__((ext_vector_type(4)));
typedef unsigned int u32x2 __attribute__((ext_vector_type(2)));

union FragU { u32x4 u4; bf16x8 bf; unsigned short us[8]; };
union XPU { u32x2 v; unsigned short us[4]; };

#define SC_SIG  -1.442695041f   // fold: sigma(x) = rcp(1 + exp2(-log2e * x))
#define SC_TANH -2.885390082f   // fold: tanh(x)  = 2*rcp(1 + exp2(-2log2e * x)) - 1

__device__ __forceinline__ unsigned short f2bf(float f){
  unsigned u = __builtin_bit_cast(unsigned, f);
  return (unsigned short)((u + 0x7FFFu + ((u>>16)&1u)) >> 16);
}
__device__ __forceinline__ float bf2f(unsigned short h){
  unsigned u = ((unsigned)h) << 16;
  return __builtin_bit_cast(float, u);
}
// y is pre-scaled by SC_SIG (or SC_TANH): returns sigma
__device__ __forceinline__ float rsig(float y){
  return __builtin_amdgcn_rcpf(1.0f + __builtin_amdgcn_exp2f(y));
}

// ---------------- merged prep: biases + both Bp weight repacks ----------------

__global__ __launch_bounds__(256) void k_prep(
    const float* __restrict__ bi0, const float* __restrict__ bh0,
    const float* __restrict__ bi1, const float* __restrict__ bh1,
    const float* __restrict__ w_ih0, const float* __restrict__ w_ih1,
    float* __restrict__ bias0, float* __restrict__ bias1,
    unsigned short* __restrict__ Bp0, unsigned short* __restrict__ Bp1)
{
  int id = blockIdx.x*256 + threadIdx.x;
  if (id < 2048){
    int n = id & 511;
    float s = ((n >> 7) == 2) ? SC_TANH : SC_SIG;
    if (id < 1024) bias0[id] = (bi0[id] + bh0[id]) * s;
    else { int k = id - 1024; bias1[k] = (bi1[k] + bh1[k]) * s; }
    return;
  }
  id -= 2048;
  if (id < 320*1024){
    int k = id >> 10, c = id & 1023;
    int dir = c >> 9, n = c & 511;
    float s = ((n >> 7) == 2) ? SC_TANH : SC_SIG;
    float v = (k < 300) ? w_ih0[((size_t)(dir*512 + n))*300 + k] * s : 0.f;
    Bp0[(((size_t)(k>>3))*1024 + c)*8 + (k&7)] = f2bf(v);
    return;
  }
  id -= 320*1024;
  if (id < 256*1024){
    int k = id >> 10, c = id & 1023;
    int dir = c >> 9, n = c & 511;
    float s = ((n >> 7) == 2) ? SC_TANH : SC_SIG;
    float v = w_ih1[((size_t)(dir*512 + n))*256 + k] * s;
    Bp1[(((size_t)(k>>3))*1024 + c)*8 + (k&7)] = f2bf(v);
  }
}

// x_emb[row][c] bf16, row = t*64+b, padded to 320 cols
__global__ __launch_bounds__(320) void k_embed(
    const int* __restrict__ word, const float* __restrict__ emb,
    unsigned short* __restrict__ xe)
{
  int row = blockIdx.x;       // 0..32767
  int c = threadIdx.x;        // 0..319
  int t = row >> 6, b = row & 63;
  int wd = word[b*TT + t];
  float v = (c < 300) ? emb[(size_t)wd*300 + c] : 0.f;
  xe[(size_t)row*320 + c] = f2bf(v);
}

// ---------------- input GEMM: xp = A(32768 x K) * Bp(K x 1024) + bias ----------------
// output scattered to xp[bid64][t][w4][lane64][4] bf16 (scan per-lane gate quads)

__global__ __launch_bounds__(256) void k_gemm(
    const unsigned short* __restrict__ A,   // [32768][lda] bf16
    const unsigned short* __restrict__ Bp,  // [K/8][1024][8] bf16
    const float* __restrict__ bias,         // [1024]
    unsigned short* __restrict__ xp,
    const int lda, const int KB)
{
  const int tid = threadIdx.x;
  const int l = tid & 63, w = tid >> 6;
  const int quad = l >> 4, lo = l & 15;
  const int wm = w >> 1, wn = w & 1;
  const int M0 = blockIdx.x * 128;
  const int N0 = blockIdx.y * 128;

  __shared__ __align__(16) unsigned short Asl[4*128*8];  // [q][m][8]
  __shared__ __align__(16) unsigned short Bsl[4*128*8];  // [q][n][8]

  f32x4 acc[4][4] = {};

  for (int kb=0; kb<KB; ++kb){
    const int k0 = kb*32;
    u32x4 va[2], vb[2];
    #pragma unroll
    for (int hh=0; hh<2; ++hh){
      const int cch = tid + hh*256;
      const int q = cch >> 7, mm = cch & 127;
      va[hh] = *(const u32x4*)(A + (size_t)(M0+mm)*lda + k0 + q*8);
      vb[hh] = *(const u32x4*)(Bp + (((size_t)((k0>>3)+q))*1024 + N0 + mm)*8);
    }
    __syncthreads();   // WAR vs previous iteration's frag reads
    #pragma unroll
    for (int hh=0; hh<2; ++hh){
      const int cch = tid + hh*256;
      *(u32x4*)&Asl[cch*8] = va[hh];
      *(u32x4*)&Bsl[cch*8] = vb[hh];
    }
    __syncthreads();

    FragU af[4], bfg[4];
    #pragma unroll
    for (int mt=0; mt<4; ++mt)
      af[mt].u4 = *(const u32x4*)&Asl[((quad<<7) + wm*64 + mt*16 + lo)*8];
    #pragma unroll
    for (int nt=0; nt<4; ++nt)
      bfg[nt].u4 = *(const u32x4*)&Bsl[((quad<<7) + wn*64 + nt*16 + lo)*8];
    #pragma unroll
    for (int mt=0; mt<4; ++mt)
      #pragma unroll
      for (int nt=0; nt<4; ++nt)
        acc[mt][nt] = __builtin_amdgcn_mfma_f32_16x16x32_bf16(af[mt].bf, bfg[nt].bf, acc[mt][nt], 0, 0, 0);
  }

  #pragma unroll
  for (int mt=0; mt<4; ++mt){
    #pragma unroll
    for (int nt=0; nt<4; ++nt){
      const int col = N0 + wn*64 + nt*16 + lo;
      const int dir = col >> 9, n = col & 511;
      const float bv = bias[col];
      const int g  = n >> 7;                 // gate type
      const int u  = n & 127;                // unit
      const int wS = u >> 5;                 // scan wave
      const int lS0 = (u & 31) * 2;          // scan lane base
      #pragma unroll
      for (int r=0; r<4; ++r){
        const int row = M0 + wm*64 + mt*16 + quad*4 + r;
        const int t = row >> 6, b = row & 63;
        const int bidS = dir*32 + (b >> 1);
        const int lS = lS0 + (b & 1);
        const size_t o = ((((size_t)bidS*TT + t)*4 + wS)*64 + lS)*4 + g;
        xp[o] = f2bf(acc[mt][nt][r] + bv);
      }
    }
  }
}

// ---------------- BiLSTM scan ----------------
// 64 WGs x 4 waves (1 wave/SIMD on 64 CUs): bid = dir*32 + bg; 2 sequences/WG.
// Per step per wave: D[batch 16][gate 128] via A=h (rows 2..15 zero),
// B = W^T static in 128 VGPRs (8 N-tiles x 4 K = 32 MFMA, parallel pipe).
// Within-wave LDS round-trip gives each lane exactly ONE (unit,batch)
// instance -> 10 transcendentals/lane. 4-phase unroll keeps store-WAR and
// prefetch-RAW >= 4 steps old; lgkm-only barrier (4 waves).

__global__ __launch_bounds__(256, 1) void k_scan(
    const float* __restrict__ w_hh,          // [2][512][128]
    const unsigned short* __restrict__ xp,   // [bid][t][w][lane][4] bf16
    unsigned short* __restrict__ xout)       // [t][64][256] bf16
{
  const int bid = blockIdx.x;           // 0..63
  const int dir = bid >> 5, bg = bid & 31;
  const int tid = threadIdx.x;          // 0..255
  const int l = tid & 63, w = tid >> 6;
  const int quad = l >> 4, lo = l & 15;
  const int up = l >> 1;                // unit-in-wave [0,32)
  const int b  = l & 1;                 // batch [0,2)

  // static weights as B-frags: tile nt covers wave-gates c = nt*16+lo;
  // g = nt>>1, unit = w*32 + (nt&1)*16 + lo;  B[k=quad*8+j][n=lo] = W[gate][k]
  FragU bw[8][4];
  {
    const float* wb = w_hh + (size_t)dir*G4*HH;
    #pragma unroll
    for (int nt=0; nt<8; ++nt){
      const int g = nt >> 1;
      const float s = (g == 2) ? SC_TANH : SC_SIG;
      const int grow = g*HH + w*32 + (nt&1)*16 + lo;
      #pragma unroll
      for (int kq=0; kq<4; ++kq){
        const float* p = wb + (size_t)grow*HH + kq*32 + quad*8;
        #pragma unroll
        for (int j=0; j<8; ++j) bw[nt][kq].us[j] = f2bf(p[j] * s);
      }
    }
  }

  __shared__ __align__(16) unsigned short hbuf[2][16][136];  // rows 2..15 stay zero
  __shared__ __align__(16) float scr[4][4][16][4];           // [wave][g][s][half*2+b]
  for (int i = tid; i < 2*16*136; i += 256) ((unsigned short*)hbuf)[i] = 0;
  __syncthreads();

  float c = 0.f;
  const int t0 = dir ? (TT-1) : 0;
  const int dt = dir ? -1 : 1;
  const unsigned short* xpb = xp + (((size_t)bid*TT*4 + w)*64 + l)*4;
  // per-step stride = 4*64*4 = 1024 elements

  // depth-4 register prefetch of xp (8 B/lane, dwordx2)
  u32x2 pf[4];
  #pragma unroll
  for (int k=0; k<4; ++k)
    pf[k] = *(const u32x2*)(xpb + (size_t)(t0 + dt*k)*1024);

  const f32x4 zero4 = {0.f, 0.f, 0.f, 0.f};

  for (int ob=0; ob<TT/4; ++ob){
    #pragma unroll
    for (int ph=0; ph<4; ++ph){
      const int it = ob*4 + ph;
      const int t = t0 + dt*it;
      const int rb = ph & 1;          // read h buffer (starts at 0)
      const int wb2 = rb ^ 1;         // write h buffer

      // A-frags: A[m=lo][k=quad*8+j] = h[batch lo][k] (rows 2..15 zero)
      FragU af[4];
      #pragma unroll
      for (int kq=0; kq<4; ++kq)
        af[kq].u4 = *(const u32x4*)&hbuf[rb][lo][kq*32 + quad*8];

      // 8 N-tiles x 4 K; C=zero4 on first K-slice (no acc-init movs)
      f32x4 acc[8];
      #pragma unroll
      for (int nt=0; nt<8; ++nt)
        acc[nt] = __builtin_amdgcn_mfma_f32_16x16x32_bf16(af[0].bf, bw[nt][0].bf, zero4, 0, 0, 0);
      #pragma unroll
      for (int kq=1; kq<4; ++kq)
        #pragma unroll
        for (int nt=0; nt<8; ++nt)
          acc[nt] = __builtin_amdgcn_mfma_f32_16x16x32_bf16(af[kq].bf, bw[nt][kq].bf, acc[nt], 0, 0, 0);

      // consume this phase's xp, then reload it for step it+4
      XPU xu; xu.v = pf[ph];
      {
        const int itp = (it+4 < TT) ? (it+4) : (TT-1);
        pf[ph] = *(const u32x2*)(xpb + (size_t)(t0 + dt*itp)*1024);
      }

      // within-wave repack: lanes quad==0 (lanes 0..15) hold D rows 0,1
      // (batches) for col lo of each tile; write pairs, read one instance.
      if (quad == 0){
        #pragma unroll
        for (int g=0; g<4; ++g){
          *(f32x2*)&scr[w][g][lo][0] = *(const f32x2*)&acc[g*2];
          *(f32x2*)&scr[w][g][lo][2] = *(const f32x2*)&acc[g*2+1];
        }
      }
      // lane owns (unit = w*32+up, batch = bg*2+b); gates g=0..3
      float gv[4];
      #pragma unroll
      for (int g=0; g<4; ++g)
        gv[g] = scr[w][g][up & 15][((up >> 4) << 1) | b] + bf2f(xu.us[g]);

      // epilogue: 1 unit per lane (pre-scaled gate values)
      float si = rsig(gv[0]), sf = rsig(gv[1]);
      float tg = __builtin_fmaf(2.0f, rsig(gv[2]), -1.0f);
      float so = rsig(gv[3]);
      c = __builtin_fmaf(sf, c, si*tg);
      float h = so * __builtin_fmaf(2.0f, rsig(SC_TANH*c), -1.0f);
      unsigned short hb = f2bf(h);
      hbuf[wb2][b][w*32 + up] = hb;
      xout[((size_t)t*NB + bg*2 + b)*HDIM + dir*HH + w*32 + up] = hb;

      // raw barrier: wait LDS only — no vmcnt drain of prefetch loads / stores
      asm volatile("s_waitcnt lgkmcnt(0)\n\ts_barrier" ::: "memory");
    }
  }
}

// ---------------- emission GEMM: em[b][t][l] = x2 row . w_out[l] + b_out[l] ----------------

__global__ __launch_bounds__(256) void k_em(
    const unsigned short* __restrict__ x2,  // [32768][256] bf16
    const float* __restrict__ w_out,        // [9][256]
    const float* __restrict__ b_out,        // [9]
    float* __restrict__ em)                 // [64][512][9]
{
  const int tid = threadIdx.x;
  const int l = tid & 63, w = tid >> 6;
  const int quad = l >> 4, lo = l & 15;
  const int M0 = blockIdx.x*128 + w*32;

  FragU bf[8];
  #pragma unroll
  for (int kq=0; kq<8; ++kq){
    #pragma unroll
    for (int j=0; j<8; ++j){
      float v = (lo < 9) ? w_out[lo*HDIM + kq*32 + quad*8 + j] : 0.f;
      bf[kq].us[j] = f2bf(v);
    }
  }

  f32x4 acc[2] = {};
  #pragma unroll
  for (int kq=0; kq<8; ++kq){
    FragU a0, a1;
    a0.u4 = *(const u32x4*)(x2 + ((size_t)(M0 + lo))*HDIM + kq*32 + quad*8);
    a1.u4 = *(const u32x4*)(x2 + ((size_t)(M0 + 16 + lo))*HDIM + kq*32 + quad*8);
    acc[0] = __builtin_amdgcn_mfma_f32_16x16x32_bf16(a0.bf, bf[kq].bf, acc[0], 0, 0, 0);
    acc[1] = __builtin_amdgcn_mfma_f32_16x16x32_bf16(a1.bf, bf[kq].bf, acc[1], 0, 0, 0);
  }

  if (lo < 9){
    const float bo = b_out[lo];
    #pragma unroll
    for (int mt=0; mt<2; ++mt){
      #pragma unroll
      for (int r=0; r<4; ++r){
        const int row = M0 + mt*16 + quad*4 + r;
        const int t = row >> 6, b = row & 63;
        em[((size_t)b*TT + t)*9 + lo] = acc[mt][r] + bo;
      }
    }
  }
}

// ---------------- CRF: fused build + radix-8 LSE-matmul reduction ----------------

__global__ __launch_bounds__(128) void k_crf_r1f(
    const int* __restrict__ word, const float* __restrict__ em,
    const float* __restrict__ start_t, const float* __restrict__ trans,
    float* __restrict__ dst)                // [64][64][81]
{
  const int bid = blockIdx.x;       // 64*64
  const int b = bid >> 6, g = bid & 63;
  const int tid = threadIdx.x;
  const int t0 = g*8;
  __shared__ float R[2][81];
  __shared__ float emsh[8][9];
  __shared__ int wsh[8];
  if (tid < 72){
    int s = tid/9, j = tid - (tid/9)*9;
    emsh[s][j] = em[((size_t)b*TT + t0+s)*9 + j];
  }
  if (tid < 8) wsh[tid] = word[b*TT + t0 + tid];
  __syncthreads();
  int i=0, j=0; float tr[9];
  if (tid < 81){
    i = tid/9; j = tid - i*9;
    #pragma unroll
    for (int k=0;k<9;++k) tr[k] = trans[k*9+j];   // trans[i][j] = tr[i]
    float v;
    if (t0 == 0) v = start_t[j] + emsh[0][j];
    else if (wsh[0] > 0) v = tr[i] + emsh[0][j];
    else v = (i==j) ? 0.f : -1e30f;
    R[0][tid] = v;
  }
  int cur = 0;
  for (int s=1; s<8; ++s){
    __syncthreads();
    if (tid < 81){
      if (wsh[s] > 0){
        float a[9], mx = -3.0e38f;
        #pragma unroll
        for (int k=0;k<9;++k){ a[k] = R[cur][i*9+k] + tr[k]; mx = fmaxf(mx, a[k]); }
        float sm = 0.f;
        #pragma unroll
        for (int k=0;k<9;++k) sm += __expf(a[k]-mx);
        R[cur^1][tid] = mx + __logf(sm) + emsh[s][j];
      } else {
        R[cur^1][tid] = R[cur][tid];
      }
    }
    cur ^= 1;
  }
  __syncthreads();
  if (tid < 81) dst[((size_t)bid)*81 + tid] = R[cur][tid];
}

// dst = radix-8 LSE-matmul reduction of src groups (order-preserving)
__global__ __launch_bounds__(128) void k_crf_reduce(
    const float* __restrict__ src, float* __restrict__ dst, const int nm)
{
  const int bid = blockIdx.x;
  const int ng = nm >> 3;
  const int b = bid / ng, g = bid - b*ng;
  const int tid = threadIdx.x;
  __shared__ float R[2][81];
  const float* base = src + ((size_t)b*nm + g*8)*81;
  if (tid < 81) R[0][tid] = base[tid];
  int cur = 0;
  for (int s=1; s<8; ++s){
    __syncthreads();
    if (tid < 81){
      int i = tid/9, j = tid - (tid/9)*9;
      const float* M = base + (size_t)s*81;
      float a[9], mx = -3.0e38f;
      #pragma unroll
      for (int k=0;k<9;++k){ a[k] = R[cur][i*9+k] + M[k*9+j]; mx = fmaxf(mx, a[k]); }
      float sm = 0.f;
      #pragma unroll
      for (int k=0;k<9;++k) sm += __expf(a[k]-mx);
      R[cur^1][tid] = mx + __logf(sm);
    }
    cur ^= 1;
  }
  __syncthreads();
  if (tid < 81) dst[((size_t)b*ng + g)*81 + tid] = R[cur][tid];
}

__global__ __launch_bounds__(256) void k_crf_num(
    const int* __restrict__ word, const int* __restrict__ label,
    const float* __restrict__ em, const float* __restrict__ start_t,
    const float* __restrict__ end_t, const float* __restrict__ trans,
    float* __restrict__ numv)
{
  const int b = blockIdx.x, tid = threadIdx.x;
  __shared__ float sred[256];
  __shared__ int ssend;
  int ms = 0;
  for (int t=tid; t<TT; t+=256) ms += (word[b*TT+t] > 0) ? 1 : 0;
  sred[tid] = (float)ms;
  __syncthreads();
  for (int st=128; st>0; st>>=1){ if (tid<st) sred[tid] += sred[tid+st]; __syncthreads(); }
  if (tid==0) ssend = (int)sred[0] - 1;
  __syncthreads();
  const int send = ssend;
  float part = 0.f;
  for (int t=tid; t<TT; t+=256){
    int tag = label[b*TT+t];
    float es = em[((size_t)b*TT+t)*9 + tag];
    if (t == 0) part += start_t[tag] + es;
    else if (word[b*TT+t] > 0) part += trans[label[b*TT+t-1]*9 + tag] + es;
    if (t == send) part += end_t[tag];
  }
  __syncthreads();
  sred[tid] = part;
  __syncthreads();
  for (int st=128; st>0; st>>=1){ if (tid<st) sred[tid] += sred[tid+st]; __syncthreads(); }
  if (tid==0) numv[b] = sred[0];
}

__global__ __launch_bounds__(64) void k_final(
    const float* __restrict__ numv, const float* __restrict__ G3,
    const float* __restrict__ end_t, float* __restrict__ out)
{
  const int b = threadIdx.x;  // 0..63
  float a[9], mx = -3.0e38f;
  #pragma unroll
  for (int j=0;j<9;++j){ a[j] = G3[b*81 + j] + end_t[j]; mx = fmaxf(mx, a[j]); }
  float sm = 0.f;
  #pragma unroll
  for (int j=0;j<9;++j) sm += __expf(a[j]-mx);
  float denom = mx + __logf(sm);
  float v = numv[b] - denom;
  #pragma unroll
  for (int off=32; off>0; off>>=1) v += __shfl_down(v, off, 64);
  if (b == 0) out[0] = -v;
}

// ---------------- launch ----------------

extern "C" void kernel_launch(void* const* d_in, const int* in_sizes, int n_in,
                              void* d_out, int out_size, void* d_ws, size_t ws_size,
                              hipStream_t stream)
{
  (void)in_sizes; (void)n_in; (void)out_size; (void)ws_size;
  const int*   word  = (const int*)d_in[0];
  const int*   label = (const int*)d_in[1];
  const float* emb   = (const float*)d_in[2];
  const float* w_ih0 = (const float*)d_in[3];
  const float* w_hh0 = (const float*)d_in[4];
  const float* b_ih0 = (const float*)d_in[5];
  const float* b_hh0 = (const float*)d_in[6];
  const float* w_ih1 = (const float*)d_in[7];
  const float* w_hh1 = (const float*)d_in[8];
  const float* b_ih1 = (const float*)d_in[9];
  const float* b_hh1 = (const float*)d_in[10];
  const float* w_out = (const float*)d_in[11];
  const float* b_out = (const float*)d_in[12];
  const float* start_t = (const float*)d_in[13];
  const float* end_t   = (const float*)d_in[14];
  const float* trans   = (const float*)d_in[15];

  char* ws = (char*)d_ws;
  unsigned short* xp    = (unsigned short*)(ws + 0);            // 67108864 B
  unsigned short* xe    = (unsigned short*)(ws + 67108864);     // 20971520 B
  unsigned short* x1    = (unsigned short*)(ws + 88080384);     // 16777216 B
  unsigned short* x2    = (unsigned short*)(ws + 104857600);    // 16777216 B
  unsigned short* Bp0   = (unsigned short*)(ws + 121634816);    // 655360 B
  unsigned short* Bp1   = (unsigned short*)(ws + 122290176);    // 524288 B
  float*          bias0 = (float*)(ws + 122814464);             // 4096 B
  float*          bias1 = (float*)(ws + 122818560);             // 4096 B
  float*          em    = (float*)(ws + 122822656);             // 1179648 B
  float*          G1    = (float*)(ws + 124002304);             // 1327104 B
  float*          G2    = (float*)(ws + 125329408);             // 165888 B
  float*          G3    = (float*)(ws + 125495296);             // 20736 B
  float*          numv  = (float*)(ws + 125516032);             // 256 B

  hipLaunchKernelGGL(k_prep, dim3(2312), dim3(256), 0, stream,
                     b_ih0, b_hh0, b_ih1, b_hh1, w_ih0, w_ih1, bias0, bias1, Bp0, Bp1);
  hipLaunchKernelGGL(k_embed, dim3(32768), dim3(320), 0, stream, word, emb, xe);
  hipLaunchKernelGGL(k_gemm, dim3(256, 8), dim3(256), 0, stream, xe, Bp0, bias0, xp, 320, 10);
  hipLaunchKernelGGL(k_scan, dim3(64), dim3(256), 0, stream, w_hh0, xp, x1);
  hipLaunchKernelGGL(k_gemm, dim3(256, 8), dim3(256), 0, stream, x1, Bp1, bias1, xp, 256, 8);
  hipLaunchKernelGGL(k_scan, dim3(64), dim3(256), 0, stream, w_hh1, xp, x2);
  hipLaunchKernelGGL(k_em, dim3(256), dim3(256), 0, stream, x2, w_out, b_out, em);
  hipLaunchKernelGGL(k_crf_r1f, dim3(4096), dim3(128), 0, stream, word, em, start_t, trans, G1);
  hipLaunchKernelGGL(k_crf_reduce, dim3(512), dim3(128), 0, stream, G1, G2, 64);
  hipLaunchKernelGGL(k_crf_reduce, dim3(64), dim3(128), 0, stream, G2, G3, 8);
  hipLaunchKernelGGL(k_crf_num, dim3(64), dim3(256), 0, stream, word, label, em, start_t, end_t, trans, numv);
  hipLaunchKernelGGL(k_final, dim3(1), dim3(64), 0, stream, numv, G3, end_t, (float*)d_out);
}

// Round 6
// 874.566 us; speedup vs baseline: 2.3038x; 1.1468x over previous
//
#include <hip/hip_runtime.h>

#define TT 512
#define NB 64
#define HH 128
#define G4 512
#define HDIM 256

typedef __bf16 bf16x8 __attribute__((ext_vector_type(8)));
typedef float f32x4 __attribute__((ext_vector_type(4)));
typedef unsigned int u32x4 __attribute__((ext_vector_type(4)));
typedef unsigned int u32x2 __attribute__((ext_vector_type(2)));

union FragU { u32x4 u4; bf16x8 bf; unsigned short us[8]; };
union XPU { u32x2 v; unsigned short us[4]; };

#define SC_SIG  -1.442695041f   // fold: sigma(x) = rcp(1 + exp2(-log2e * x))
#define SC_TANH -2.885390082f   // fold: tanh(x)  = 2*rcp(1 + exp2(-2log2e * x)) - 1

__device__ __forceinline__ unsigned short f2bf(float f){
  unsigned u = __builtin_bit_cast(unsigned, f);
  return (unsigned short)((u + 0x7FFFu + ((u>>16)&1u)) >> 16);
}
__device__ __forceinline__ float bf2f(unsigned short h){
  unsigned u = ((unsigned)h) << 16;
  return __builtin_bit_cast(float, u);
}
// y is pre-scaled by SC_SIG (or SC_TANH): returns sigma
__device__ __forceinline__ float rsig(float y){
  return __builtin_amdgcn_rcpf(1.0f + __builtin_amdgcn_exp2f(y));
}

// ---------------- merged prep: biases + both Bp weight repacks ----------------

__global__ __launch_bounds__(256) void k_prep(
    const float* __restrict__ bi0, const float* __restrict__ bh0,
    const float* __restrict__ bi1, const float* __restrict__ bh1,
    const float* __restrict__ w_ih0, const float* __restrict__ w_ih1,
    float* __restrict__ bias0, float* __restrict__ bias1,
    unsigned short* __restrict__ Bp0, unsigned short* __restrict__ Bp1)
{
  int id = blockIdx.x*256 + threadIdx.x;
  if (id < 2048){
    int n = id & 511;
    float s = ((n >> 7) == 2) ? SC_TANH : SC_SIG;
    if (id < 1024) bias0[id] = (bi0[id] + bh0[id]) * s;
    else { int k = id - 1024; bias1[k] = (bi1[k] + bh1[k]) * s; }
    return;
  }
  id -= 2048;
  if (id < 320*1024){
    int k = id >> 10, c = id & 1023;
    int dir = c >> 9, n = c & 511;
    float s = ((n >> 7) == 2) ? SC_TANH : SC_SIG;
    float v = (k < 300) ? w_ih0[((size_t)(dir*512 + n))*300 + k] * s : 0.f;
    Bp0[(((size_t)(k>>3))*1024 + c)*8 + (k&7)] = f2bf(v);
    return;
  }
  id -= 320*1024;
  if (id < 256*1024){
    int k = id >> 10, c = id & 1023;
    int dir = c >> 9, n = c & 511;
    float s = ((n >> 7) == 2) ? SC_TANH : SC_SIG;
    float v = w_ih1[((size_t)(dir*512 + n))*256 + k] * s;
    Bp1[(((size_t)(k>>3))*1024 + c)*8 + (k&7)] = f2bf(v);
  }
}

// x_emb[row][c] bf16, row = t*64+b, padded to 320 cols
__global__ __launch_bounds__(320) void k_embed(
    const int* __restrict__ word, const float* __restrict__ emb,
    unsigned short* __restrict__ xe)
{
  int row = blockIdx.x;       // 0..32767
  int c = threadIdx.x;        // 0..319
  int t = row >> 6, b = row & 63;
  int wd = word[b*TT + t];
  float v = (c < 300) ? emb[(size_t)wd*300 + c] : 0.f;
  xe[(size_t)row*320 + c] = f2bf(v);
}

// ---------------- input GEMM: xp = A(32768 x K) * Bp(K x 1024) + bias ----------------
// output layout: xp[t][b64][dir][u128][g4] bf16 = row*1024 + dir*512 + u*4 + g
// (row-local stride-8B scatter; matches scan's per-lane 8B gate quads)

__global__ __launch_bounds__(256) void k_gemm(
    const unsigned short* __restrict__ A,   // [32768][lda] bf16
    const unsigned short* __restrict__ Bp,  // [K/8][1024][8] bf16
    const float* __restrict__ bias,         // [1024]
    unsigned short* __restrict__ xp,
    const int lda, const int KB)
{
  const int tid = threadIdx.x;
  const int l = tid & 63, w = tid >> 6;
  const int quad = l >> 4, lo = l & 15;
  const int wm = w >> 1, wn = w & 1;
  const int M0 = blockIdx.x * 128;
  const int N0 = blockIdx.y * 128;

  __shared__ __align__(16) unsigned short Asl[4*128*8];  // [q][m][8]
  __shared__ __align__(16) unsigned short Bsl[4*128*8];  // [q][n][8]

  f32x4 acc[4][4] = {};

  for (int kb=0; kb<KB; ++kb){
    const int k0 = kb*32;
    u32x4 va[2], vb[2];
    #pragma unroll
    for (int hh=0; hh<2; ++hh){
      const int cch = tid + hh*256;
      const int q = cch >> 7, mm = cch & 127;
      va[hh] = *(const u32x4*)(A + (size_t)(M0+mm)*lda + k0 + q*8);
      vb[hh] = *(const u32x4*)(Bp + (((size_t)((k0>>3)+q))*1024 + N0 + mm)*8);
    }
    __syncthreads();   // WAR vs previous iteration's frag reads
    #pragma unroll
    for (int hh=0; hh<2; ++hh){
      const int cch = tid + hh*256;
      *(u32x4*)&Asl[cch*8] = va[hh];
      *(u32x4*)&Bsl[cch*8] = vb[hh];
    }
    __syncthreads();

    FragU af[4], bfg[4];
    #pragma unroll
    for (int mt=0; mt<4; ++mt)
      af[mt].u4 = *(const u32x4*)&Asl[((quad<<7) + wm*64 + mt*16 + lo)*8];
    #pragma unroll
    for (int nt=0; nt<4; ++nt)
      bfg[nt].u4 = *(const u32x4*)&Bsl[((quad<<7) + wn*64 + nt*16 + lo)*8];
    #pragma unroll
    for (int mt=0; mt<4; ++mt)
      #pragma unroll
      for (int nt=0; nt<4; ++nt)
        acc[mt][nt] = __builtin_amdgcn_mfma_f32_16x16x32_bf16(af[mt].bf, bfg[nt].bf, acc[mt][nt], 0, 0, 0);
  }

  #pragma unroll
  for (int mt=0; mt<4; ++mt){
    #pragma unroll
    for (int nt=0; nt<4; ++nt){
      const int col = N0 + wn*64 + nt*16 + lo;
      const int dir = col >> 9, n = col & 511;
      const int g = n >> 7, u = n & 127;
      const float bv = bias[col];
      #pragma unroll
      for (int r=0; r<4; ++r){
        const int row = M0 + wm*64 + mt*16 + quad*4 + r;
        const size_t o = (size_t)row*1024 + dir*512 + u*4 + g;
        xp[o] = f2bf(acc[mt][nt][r] + bv);
      }
    }
  }
}

// ---------------- BiLSTM scan ----------------
// 64 WGs x 4 waves (1 wave/SIMD on 64 CUs): bid = dir*32 + bg; 2 seqs/WG.
// Replicated-A trick: A[m][k] = h[m&1][k] (batch = row parity, replicated).
// MFMA D then replicates gates across quads -> EVERY lane holds both batches
// for its 2 unit-columns in acc regs; lane selects its one (unit,batch)
// instance with 12 cndmask (no LDS gate round-trip). af reads are 8-lane
// same-address broadcasts (conflict-free). hbuf = 2 rows only.
// 4-phase unroll keeps store-WAR / prefetch-RAW >= 4 steps old;
// lgkm-only barrier keeps VMEM off the per-step critical path.

__global__ __launch_bounds__(256, 1) void k_scan(
    const float* __restrict__ w_hh,          // [2][512][128]
    const unsigned short* __restrict__ xp,   // [t][64][2][128][4] bf16
    unsigned short* __restrict__ xout)       // [t][64][256] bf16
{
  const int bid = blockIdx.x;           // 0..63
  const int dir = bid >> 5, bg = bid & 31;
  const int tid = threadIdx.x;          // 0..255
  const int l = tid & 63, w = tid >> 6;
  const int quad = l >> 4, lo = l & 15;
  const int qb = quad & 1;              // owned batch (0/1)
  const int qh = quad >> 1;             // owned unit-half (0/1)
  const int uu = w*32 + qh*16 + lo;     // owned unit [0,128)
  const int bglob = bg*2 + qb;          // owned global batch

  // static weights as B-frags: tile nt: gate g=nt>>1, units w*32+(nt&1)*16+lo
  FragU bw[8][4];
  {
    const float* wb = w_hh + (size_t)dir*G4*HH;
    #pragma unroll
    for (int nt=0; nt<8; ++nt){
      const int g = nt >> 1;
      const float s = (g == 2) ? SC_TANH : SC_SIG;
      const int grow = g*HH + w*32 + (nt&1)*16 + lo;
      #pragma unroll
      for (int kq=0; kq<4; ++kq){
        const float* p = wb + (size_t)grow*HH + kq*32 + quad*8;
        #pragma unroll
        for (int j=0; j<8; ++j) bw[nt][kq].us[j] = f2bf(p[j] * s);
      }
    }
  }

  __shared__ __align__(16) unsigned short hbuf[2][2][160];  // [buf][batch][k]
  for (int i = tid; i < 2*2*160; i += 256) ((unsigned short*)hbuf)[i] = 0;
  __syncthreads();

  float c = 0.f;
  const int t0 = dir ? (TT-1) : 0;
  const int dt = dir ? -1 : 1;
  const unsigned short* xpb = xp + (size_t)bglob*1024 + dir*512 + uu*4;
  unsigned short* xob = xout + (size_t)bglob*HDIM + dir*HH + uu;

  // depth-4 register prefetch of xp (8 B/lane, dwordx2); step stride 65536
  u32x2 pf[4];
  #pragma unroll
  for (int k=0; k<4; ++k)
    pf[k] = *(const u32x2*)(xpb + (size_t)(t0 + dt*k)*65536);

  const f32x4 zero4 = {0.f, 0.f, 0.f, 0.f};

  for (int ob=0; ob<TT/4; ++ob){
    #pragma unroll
    for (int ph=0; ph<4; ++ph){
      const int it = ob*4 + ph;
      const int t = t0 + dt*it;
      const int rb = ph & 1;          // read h buffer (starts at 0)
      const int wb2 = rb ^ 1;         // write h buffer

      // A-frags: A[m=lo][k=kq*32+quad*8+j] = h[lo&1][k]  (broadcast reads)
      FragU af[4];
      #pragma unroll
      for (int kq=0; kq<4; ++kq)
        af[kq].u4 = *(const u32x4*)&hbuf[rb][lo & 1][kq*32 + quad*8];

      // 8 N-tiles x 4 K; C=zero4 on first K-slice (no acc-init movs)
      f32x4 acc[8];
      #pragma unroll
      for (int nt=0; nt<8; ++nt)
        acc[nt] = __builtin_amdgcn_mfma_f32_16x16x32_bf16(af[0].bf, bw[nt][0].bf, zero4, 0, 0, 0);
      #pragma unroll
      for (int kq=1; kq<4; ++kq)
        #pragma unroll
        for (int nt=0; nt<8; ++nt)
          acc[nt] = __builtin_amdgcn_mfma_f32_16x16x32_bf16(af[kq].bf, bw[nt][kq].bf, acc[nt], 0, 0, 0);

      // consume this phase's xp, then reload it for step it+4
      XPU xu; xu.v = pf[ph];
      {
        const int itp = (it+4 < TT) ? (it+4) : (TT-1);
        pf[ph] = *(const u32x2*)(xpb + (size_t)(t0 + dt*itp)*65536);
      }

      // select own instance: reg r=qb (batch), tile half = qh
      float gv[4];
      #pragma unroll
      for (int g=0; g<4; ++g){
        float ta = qb ? acc[g*2  ][1] : acc[g*2  ][0];
        float tb = qb ? acc[g*2+1][1] : acc[g*2+1][0];
        gv[g] = (qh ? tb : ta) + bf2f(xu.us[g]);
      }

      // epilogue: 1 unit per lane (pre-scaled gate values)
      float si = rsig(gv[0]), sf = rsig(gv[1]);
      float tg = __builtin_fmaf(2.0f, rsig(gv[2]), -1.0f);
      float so = rsig(gv[3]);
      c = __builtin_fmaf(sf, c, si*tg);
      float h = so * __builtin_fmaf(2.0f, rsig(SC_TANH*c), -1.0f);
      unsigned short hb = f2bf(h);
      hbuf[wb2][qb][uu] = hb;
      xob[(size_t)t*NB*HDIM] = hb;

      // raw barrier: wait LDS only — no vmcnt drain of prefetch loads / stores
      asm volatile("s_waitcnt lgkmcnt(0)\n\ts_barrier" ::: "memory");
    }
  }
}

// ---------------- emission GEMM: em[b][t][l] = x2 row . w_out[l] + b_out[l] ----------------

__global__ __launch_bounds__(256) void k_em(
    const unsigned short* __restrict__ x2,  // [32768][256] bf16
    const float* __restrict__ w_out,        // [9][256]
    const float* __restrict__ b_out,        // [9]
    float* __restrict__ em)                 // [64][512][9]
{
  const int tid = threadIdx.x;
  const int l = tid & 63, w = tid >> 6;
  const int quad = l >> 4, lo = l & 15;
  const int M0 = blockIdx.x*128 + w*32;

  FragU bf[8];
  #pragma unroll
  for (int kq=0; kq<8; ++kq){
    #pragma unroll
    for (int j=0; j<8; ++j){
      float v = (lo < 9) ? w_out[lo*HDIM + kq*32 + quad*8 + j] : 0.f;
      bf[kq].us[j] = f2bf(v);
    }
  }

  f32x4 acc[2] = {};
  #pragma unroll
  for (int kq=0; kq<8; ++kq){
    FragU a0, a1;
    a0.u4 = *(const u32x4*)(x2 + ((size_t)(M0 + lo))*HDIM + kq*32 + quad*8);
    a1.u4 = *(const u32x4*)(x2 + ((size_t)(M0 + 16 + lo))*HDIM + kq*32 + quad*8);
    acc[0] = __builtin_amdgcn_mfma_f32_16x16x32_bf16(a0.bf, bf[kq].bf, acc[0], 0, 0, 0);
    acc[1] = __builtin_amdgcn_mfma_f32_16x16x32_bf16(a1.bf, bf[kq].bf, acc[1], 0, 0, 0);
  }

  if (lo < 9){
    const float bo = b_out[lo];
    #pragma unroll
    for (int mt=0; mt<2; ++mt){
      #pragma unroll
      for (int r=0; r<4; ++r){
        const int row = M0 + mt*16 + quad*4 + r;
        const int t = row >> 6, b = row & 63;
        em[((size_t)b*TT + t)*9 + lo] = acc[mt][r] + bo;
      }
    }
  }
}

// ---------------- CRF: fused build + radix-8 LSE-matmul reduction ----------------

__global__ __launch_bounds__(128) void k_crf_r1f(
    const int* __restrict__ word, const float* __restrict__ em,
    const float* __restrict__ start_t, const float* __restrict__ trans,
    float* __restrict__ dst)                // [64][64][81]
{
  const int bid = blockIdx.x;       // 64*64
  const int b = bid >> 6, g = bid & 63;
  const int tid = threadIdx.x;
  const int t0 = g*8;
  __shared__ float R[2][81];
  __shared__ float emsh[8][9];
  __shared__ int wsh[8];
  if (tid < 72){
    int s = tid/9, j = tid - (tid/9)*9;
    emsh[s][j] = em[((size_t)b*TT + t0+s)*9 + j];
  }
  if (tid < 8) wsh[tid] = word[b*TT + t0 + tid];
  __syncthreads();
  int i=0, j=0; float tr[9];
  if (tid < 81){
    i = tid/9; j = tid - i*9;
    #pragma unroll
    for (int k=0;k<9;++k) tr[k] = trans[k*9+j];   // trans[i][j] = tr[i]
    float v;
    if (t0 == 0) v = start_t[j] + emsh[0][j];
    else if (wsh[0] > 0) v = tr[i] + emsh[0][j];
    else v = (i==j) ? 0.f : -1e30f;
    R[0][tid] = v;
  }
  int cur = 0;
  for (int s=1; s<8; ++s){
    __syncthreads();
    if (tid < 81){
      if (wsh[s] > 0){
        float a[9], mx = -3.0e38f;
        #pragma unroll
        for (int k=0;k<9;++k){ a[k] = R[cur][i*9+k] + tr[k]; mx = fmaxf(mx, a[k]); }
        float sm = 0.f;
        #pragma unroll
        for (int k=0;k<9;++k) sm += __expf(a[k]-mx);
        R[cur^1][tid] = mx + __logf(sm) + emsh[s][j];
      } else {
        R[cur^1][tid] = R[cur][tid];
      }
    }
    cur ^= 1;
  }
  __syncthreads();
  if (tid < 81) dst[((size_t)bid)*81 + tid] = R[cur][tid];
}

// dst = radix-8 LSE-matmul reduction of src groups (order-preserving)
__global__ __launch_bounds__(128) void k_crf_reduce(
    const float* __restrict__ src, float* __restrict__ dst, const int nm)
{
  const int bid = blockIdx.x;
  const int ng = nm >> 3;
  const int b = bid / ng, g = bid - b*ng;
  const int tid = threadIdx.x;
  __shared__ float R[2][81];
  const float* base = src + ((size_t)b*nm + g*8)*81;
  if (tid < 81) R[0][tid] = base[tid];
  int cur = 0;
  for (int s=1; s<8; ++s){
    __syncthreads();
    if (tid < 81){
      int i = tid/9, j = tid - (tid/9)*9;
      const float* M = base + (size_t)s*81;
      float a[9], mx = -3.0e38f;
      #pragma unroll
      for (int k=0;k<9;++k){ a[k] = R[cur][i*9+k] + M[k*9+j]; mx = fmaxf(mx, a[k]); }
      float sm = 0.f;
      #pragma unroll
      for (int k=0;k<9;++k) sm += __expf(a[k]-mx);
      R[cur^1][tid] = mx + __logf(sm);
    }
    cur ^= 1;
  }
  __syncthreads();
  if (tid < 81) dst[((size_t)b*ng + g)*81 + tid] = R[cur][tid];
}

__global__ __launch_bounds__(256) void k_crf_num(
    const int* __restrict__ word, const int* __restrict__ label,
    const float* __restrict__ em, const float* __restrict__ start_t,
    const float* __restrict__ end_t, const float* __restrict__ trans,
    float* __restrict__ numv)
{
  const int b = blockIdx.x, tid = threadIdx.x;
  __shared__ float sred[256];
  __shared__ int ssend;
  int ms = 0;
  for (int t=tid; t<TT; t+=256) ms += (word[b*TT+t] > 0) ? 1 : 0;
  sred[tid] = (float)ms;
  __syncthreads();
  for (int st=128; st>0; st>>=1){ if (tid<st) sred[tid] += sred[tid+st]; __syncthreads(); }
  if (tid==0) ssend = (int)sred[0] - 1;
  __syncthreads();
  const int send = ssend;
  float part = 0.f;
  for (int t=tid; t<TT; t+=256){
    int tag = label[b*TT+t];
    float es = em[((size_t)b*TT+t)*9 + tag];
    if (t == 0) part += start_t[tag] + es;
    else if (word[b*TT+t] > 0) part += trans[label[b*TT+t-1]*9 + tag] + es;
    if (t == send) part += end_t[tag];
  }
  __syncthreads();
  sred[tid] = part;
  __syncthreads();
  for (int st=128; st>0; st>>=1){ if (tid<st) sred[tid] += sred[tid+st]; __syncthreads(); }
  if (tid==0) numv[b] = sred[0];
}

__global__ __launch_bounds__(64) void k_final(
    const float* __restrict__ numv, const float* __restrict__ G3,
    const float* __restrict__ end_t, float* __restrict__ out)
{
  const int b = threadIdx.x;  // 0..63
  float a[9], mx = -3.0e38f;
  #pragma unroll
  for (int j=0;j<9;++j){ a[j] = G3[b*81 + j] + end_t[j]; mx = fmaxf(mx, a[j]); }
  float sm = 0.f;
  #pragma unroll
  for (int j=0;j<9;++j) sm += __expf(a[j]-mx);
  float denom = mx + __logf(sm);
  float v = numv[b] - denom;
  #pragma unroll
  for (int off=32; off>0; off>>=1) v += __shfl_down(v, off, 64);
  if (b == 0) out[0] = -v;
}

// ---------------- launch ----------------

extern "C" void kernel_launch(void* const* d_in, const int* in_sizes, int n_in,
                              void* d_out, int out_size, void* d_ws, size_t ws_size,
                              hipStream_t stream)
{
  (void)in_sizes; (void)n_in; (void)out_size; (void)ws_size;
  const int*   word  = (const int*)d_in[0];
  const int*   label = (const int*)d_in[1];
  const float* emb   = (const float*)d_in[2];
  const float* w_ih0 = (const float*)d_in[3];
  const float* w_hh0 = (const float*)d_in[4];
  const float* b_ih0 = (const float*)d_in[5];
  const float* b_hh0 = (const float*)d_in[6];
  const float* w_ih1 = (const float*)d_in[7];
  const float* w_hh1 = (const float*)d_in[8];
  const float* b_ih1 = (const float*)d_in[9];
  const float* b_hh1 = (const float*)d_in[10];
  const float* w_out = (const float*)d_in[11];
  const float* b_out = (const float*)d_in[12];
  const float* start_t = (const float*)d_in[13];
  const float* end_t   = (const float*)d_in[14];
  const float* trans   = (const float*)d_in[15];

  char* ws = (char*)d_ws;
  unsigned short* xp    = (unsigned short*)(ws + 0);            // 67108864 B
  unsigned short* xe    = (unsigned short*)(ws + 67108864);     // 20971520 B
  unsigned short* x1    = (unsigned short*)(ws + 88080384);     // 16777216 B
  unsigned short* x2    = (unsigned short*)(ws + 104857600);    // 16777216 B
  unsigned short* Bp0   = (unsigned short*)(ws + 121634816);    // 655360 B
  unsigned short* Bp1   = (unsigned short*)(ws + 122290176);    // 524288 B
  float*          bias0 = (float*)(ws + 122814464);             // 4096 B
  float*          bias1 = (float*)(ws + 122818560);             // 4096 B
  float*          em    = (float*)(ws + 122822656);             // 1179648 B
  float*          G1    = (float*)(ws + 124002304);             // 1327104 B
  float*          G2    = (float*)(ws + 125329408);             // 165888 B
  float*          G3    = (float*)(ws + 125495296);             // 20736 B
  float*          numv  = (float*)(ws + 125516032);             // 256 B

  hipLaunchKernelGGL(k_prep, dim3(2312), dim3(256), 0, stream,
                     b_ih0, b_hh0, b_ih1, b_hh1, w_ih0, w_ih1, bias0, bias1, Bp0, Bp1);
  hipLaunchKernelGGL(k_embed, dim3(32768), dim3(320), 0, stream, word, emb, xe);
  hipLaunchKernelGGL(k_gemm, dim3(256, 8), dim3(256), 0, stream, xe, Bp0, bias0, xp, 320, 10);
  hipLaunchKernelGGL(k_scan, dim3(64), dim3(256), 0, stream, w_hh0, xp, x1);
  hipLaunchKernelGGL(k_gemm, dim3(256, 8), dim3(256), 0, stream, x1, Bp1, bias1, xp, 256, 8);
  hipLaunchKernelGGL(k_scan, dim3(64), dim3(256), 0, stream, w_hh1, xp, x2);
  hipLaunchKernelGGL(k_em, dim3(256), dim3(256), 0, stream, x2, w_out, b_out, em);
  hipLaunchKernelGGL(k_crf_r1f, dim3(4096), dim3(128), 0, stream, word, em, start_t, trans, G1);
  hipLaunchKernelGGL(k_crf_reduce, dim3(512), dim3(128), 0, stream, G1, G2, 64);
  hipLaunchKernelGGL(k_crf_reduce, dim3(64), dim3(128), 0, stream, G2, G3, 8);
  hipLaunchKernelGGL(k_crf_num, dim3(64), dim3(256), 0, stream, word, label, em, start_t, end_t, trans, numv);
  hipLaunchKernelGGL(k_final, dim3(1), dim3(64), 0, stream, numv, G3, end_t, (float*)d_out);
}